// Round 1
// baseline (12525.481 us; speedup 1.0000x reference)
//
#include <hip/hip_runtime.h>

#define N_NODES  50000
#define G_NUM    4
#define N_EDGES  800000
#define IN_FEATS 256
#define H_FEATS  128
#define NUM_CLS  40
#define CAT      512   // H_FEATS * G_NUM

// ---------------- degree accumulation ----------------
__global__ void k_deg(const int* __restrict__ idx, float* __restrict__ deg) {
    int stride = gridDim.x * blockDim.x;
    int total = G_NUM * N_EDGES;
    for (int i = blockIdx.x * blockDim.x + threadIdx.x; i < total; i += stride) {
        int g = i / N_EDGES;                 // magic-mul by compiler
        atomicAdd(&deg[g * N_NODES + idx[i]], 1.0f);
    }
}

__global__ void k_invsqrt(float* __restrict__ d, int n) {
    int stride = gridDim.x * blockDim.x;
    for (int i = blockIdx.x * blockDim.x + threadIdx.x; i < n; i += stride)
        d[i] = rsqrtf(fmaxf(d[i], 1.0f));
}

// ---------------- fp32 tiled GEMM: C[M,N] = act(A[M,K] @ B[K,N] + bias) ----------------
template<bool RELU, bool HASBIAS>
__global__ __launch_bounds__(256, 2) void k_gemm(
        const float* __restrict__ A, const float* __restrict__ B,
        const float* __restrict__ bias, float* __restrict__ C,
        int M, int N, int K) {
    constexpr int BM = 128, BN = 128, BK = 8;
    __shared__ float sA[BK][BM + 4];
    __shared__ float sB[BK][BN + 4];
    const int tid = threadIdx.x;
    const int bm = blockIdx.y * BM, bn = blockIdx.x * BN;
    const int tx = tid & 15, ty = tid >> 4;   // 16x16 threads, 8x8 each
    float acc[8][8] = {};

    for (int k0 = 0; k0 < K; k0 += BK) {
        // A tile: 128 rows x 8 cols, one float4 per thread
        {
            int r = tid >> 1;
            int c = (tid & 1) * 4;
            int gr = bm + r;
            float4 v = make_float4(0.f, 0.f, 0.f, 0.f);
            if (gr < M)
                v = *reinterpret_cast<const float4*>(&A[(size_t)gr * K + k0 + c]);
            sA[c + 0][r] = v.x; sA[c + 1][r] = v.y;
            sA[c + 2][r] = v.z; sA[c + 3][r] = v.w;
        }
        // B tile: 8 rows x 128 cols
        {
            int col = tid & 127;
            int r0 = tid >> 7;  // 0..1
            #pragma unroll
            for (int r = r0; r < BK; r += 2) {
                float v = 0.f;
                if (bn + col < N) v = B[(size_t)(k0 + r) * N + bn + col];
                sB[r][col] = v;
            }
        }
        __syncthreads();
        #pragma unroll
        for (int k = 0; k < BK; k++) {
            float a[8], b[8];
            #pragma unroll
            for (int i = 0; i < 8; i++) a[i] = sA[k][ty * 8 + i];
            #pragma unroll
            for (int j = 0; j < 8; j++) b[j] = sB[k][tx * 8 + j];
            #pragma unroll
            for (int i = 0; i < 8; i++)
                #pragma unroll
                for (int j = 0; j < 8; j++)
                    acc[i][j] = fmaf(a[i], b[j], acc[i][j]);
        }
        __syncthreads();
    }
    // epilogue
    #pragma unroll
    for (int i = 0; i < 8; i++) {
        int gr = bm + ty * 8 + i;
        if (gr >= M) continue;
        #pragma unroll
        for (int j = 0; j < 8; j++) {
            int gc = bn + tx * 8 + j;
            if (gc >= N) continue;
            float v = acc[i][j];
            if (HASBIAS) v += bias[gc];
            if (RELU) v = fmaxf(v, 0.f);
            C[(size_t)gr * N + gc] = v;
        }
    }
}

// ---------------- SpMM scatter: H[dst, g*128 + :] += P[src,:] * (w * invdegout[g,src]) ----------------
__global__ void k_spmm(const float* __restrict__ P, const int* __restrict__ src,
                       const int* __restrict__ dst, const float* __restrict__ w,
                       const float* __restrict__ invdegout, float* __restrict__ H) {
    // work item i = (t, q): t = g*E + e edge index, q = float4 chunk (0..31)
    long long total = (long long)G_NUM * N_EDGES * 32;
    long long stride = (long long)gridDim.x * blockDim.x;
    for (long long i = (long long)blockIdx.x * blockDim.x + threadIdx.x; i < total; i += stride) {
        int q = (int)(i & 31);
        int t = (int)(i >> 5);
        int g = t / N_EDGES;
        int s = src[t], d = dst[t];
        float coef = w[t] * invdegout[g * N_NODES + s];
        float4 v = *reinterpret_cast<const float4*>(&P[(size_t)s * H_FEATS + q * 4]);
        float* out = &H[(size_t)d * CAT + g * H_FEATS + q * 4];
        atomicAdd(out + 0, v.x * coef);
        atomicAdd(out + 1, v.y * coef);
        atomicAdd(out + 2, v.z * coef);
        atomicAdd(out + 3, v.w * coef);
    }
}

// ---------------- post-conv: H = relu(H * invdegin[g, n]) ----------------
__global__ void k_postconv(float* __restrict__ H, const float* __restrict__ invdegin) {
    int total = N_NODES * (CAT / 4);
    int stride = gridDim.x * blockDim.x;
    for (int i4 = blockIdx.x * blockDim.x + threadIdx.x; i4 < total; i4 += stride) {
        int n = i4 >> 7;              // CAT/4 = 128 float4 per row
        int c4 = (i4 & 127) * 4;
        int g = c4 >> 7;
        float s = invdegin[g * N_NODES + n];
        float4* p = reinterpret_cast<float4*>(&H[(size_t)n * CAT + c4]);
        float4 v = *p;
        v.x = fmaxf(v.x * s, 0.f); v.y = fmaxf(v.y * s, 0.f);
        v.z = fmaxf(v.z * s, 0.f); v.w = fmaxf(v.w * s, 0.f);
        *p = v;
    }
}

extern "C" void kernel_launch(void* const* d_in, const int* in_sizes, int n_in,
                              void* d_out, int out_size, void* d_ws, size_t ws_size,
                              hipStream_t stream) {
    const float* in_feat = (const float*)d_in[0];
    const int*   src     = (const int*)d_in[1];
    const int*   dst     = (const int*)d_in[2];
    const float* w       = (const float*)d_in[3];
    const float* W1      = (const float*)d_in[4];
    const float* W2      = (const float*)d_in[5];
    const float* l1w     = (const float*)d_in[6];
    const float* l1b     = (const float*)d_in[7];
    const float* l2w     = (const float*)d_in[8];
    const float* l2b     = (const float*)d_in[9];
    const float* l3w     = (const float*)d_in[10];
    const float* l3b     = (const float*)d_in[11];
    float* out = (float*)d_out;

    float* ws = (float*)d_ws;
    float* P   = ws;                         // 50000*128 = 6.4M floats
    float* H1  = P  + (size_t)N_NODES * H_FEATS;   // 25.6M floats
    float* H2  = H1 + (size_t)N_NODES * CAT;       // 25.6M floats
    float* dgo = H2 + (size_t)N_NODES * CAT;       // 4*50000
    float* dgi = dgo + (size_t)G_NUM * N_NODES;    // 4*50000

    const int TPB = 256;
    dim3 blk(TPB);

    // 1. degrees
    hipMemsetAsync(dgo, 0, 2 * (size_t)G_NUM * N_NODES * sizeof(float), stream);
    k_deg<<<2048, blk, 0, stream>>>(src, dgo);
    k_deg<<<2048, blk, 0, stream>>>(dst, dgi);
    k_invsqrt<<<1024, blk, 0, stream>>>(dgo, 2 * G_NUM * N_NODES);

    dim3 gP(1, (N_NODES + 127) / 128);       // N=128
    dim3 gC((CAT + 127) / 128, (N_NODES + 127) / 128);
    dim3 gO(1, (N_NODES + 127) / 128);       // N=40

    // 2. P = in_feat @ W1
    k_gemm<false, false><<<gP, blk, 0, stream>>>(in_feat, W1, nullptr, P,
                                                 N_NODES, H_FEATS, IN_FEATS);
    // 3. conv1 scatter into H1
    hipMemsetAsync(H1, 0, (size_t)N_NODES * CAT * sizeof(float), stream);
    k_spmm<<<8192, blk, 0, stream>>>(P, src, dst, w, dgo, H1);
    k_postconv<<<8192, blk, 0, stream>>>(H1, dgi);

    // 4. H2 = relu(H1 @ l1w + l1b)
    k_gemm<true, true><<<gC, blk, 0, stream>>>(H1, l1w, l1b, H2, N_NODES, CAT, CAT);
    // 5. H1 = relu(H2 @ l2w + l2b)
    k_gemm<true, true><<<gC, blk, 0, stream>>>(H2, l2w, l2b, H1, N_NODES, CAT, CAT);

    // 6. P = H1 @ W2
    k_gemm<false, false><<<gP, blk, 0, stream>>>(H1, W2, nullptr, P,
                                                 N_NODES, H_FEATS, CAT);
    // 7. conv2 scatter into H2
    hipMemsetAsync(H2, 0, (size_t)N_NODES * CAT * sizeof(float), stream);
    k_spmm<<<8192, blk, 0, stream>>>(P, src, dst, w, dgo, H2);
    k_postconv<<<8192, blk, 0, stream>>>(H2, dgi);

    // 8. out = H2 @ l3w + l3b
    k_gemm<false, true><<<gO, blk, 0, stream>>>(H2, l3w, l3b, out,
                                                N_NODES, NUM_CLS, CAT);
}

// Round 2
// 2244.235 us; speedup vs baseline: 5.5812x; 5.5812x over previous
//
#include <hip/hip_runtime.h>

#define N_NODES  50000
#define G_NUM    4
#define N_EDGES  800000
#define IN_FEATS 256
#define H_FEATS  128
#define NUM_CLS  40
#define CAT      512   // H_FEATS * G_NUM
#define NNG      (G_NUM * N_NODES)   // 200000
#define TOT_E    (G_NUM * N_EDGES)   // 3200000

// ---------------- degree accumulation (int) ----------------
__global__ void k_deg_i(const int* __restrict__ idx, int* __restrict__ deg) {
    int stride = gridDim.x * blockDim.x;
    for (int i = blockIdx.x * blockDim.x + threadIdx.x; i < TOT_E; i += stride) {
        int g = i / N_EDGES;
        atomicAdd(&deg[g * N_NODES + idx[i]], 1);
    }
}

__global__ void k_invsqrt_i(const int* __restrict__ d, float* __restrict__ f, int n) {
    int stride = gridDim.x * blockDim.x;
    for (int i = blockIdx.x * blockDim.x + threadIdx.x; i < n; i += stride)
        f[i] = rsqrtf(fmaxf((float)d[i], 1.0f));
}

// ---------------- exclusive scan of deg_in (200000 elems) ----------------
// K1: 256 elems/block -> partial exclusive scans + block sums
__global__ void k_scan1(const int* __restrict__ deg, int* __restrict__ cursor,
                        int* __restrict__ partials) {
    __shared__ int s[256];
    int i = blockIdx.x * 256 + threadIdx.x;
    int v = (i < NNG) ? deg[i] : 0;
    s[threadIdx.x] = v;
    __syncthreads();
    for (int off = 1; off < 256; off <<= 1) {
        int t = (threadIdx.x >= off) ? s[threadIdx.x - off] : 0;
        __syncthreads();
        s[threadIdx.x] += t;
        __syncthreads();
    }
    if (i < NNG) cursor[i] = s[threadIdx.x] - v;   // exclusive, pre-partial
    if (threadIdx.x == 255) partials[blockIdx.x] = s[255];
}
// K2: single block scans the 782 block sums (n <= 1024)
__global__ void k_scan2(int* __restrict__ partials, int n) {
    __shared__ int s[1024];
    int v = (threadIdx.x < n) ? partials[threadIdx.x] : 0;
    s[threadIdx.x] = v;
    __syncthreads();
    for (int off = 1; off < 1024; off <<= 1) {
        int t = (threadIdx.x >= off) ? s[threadIdx.x - off] : 0;
        __syncthreads();
        s[threadIdx.x] += t;
        __syncthreads();
    }
    if (threadIdx.x < n) partials[threadIdx.x] = s[threadIdx.x] - v;  // exclusive
}
// K3: add block offsets
__global__ void k_scan3(int* __restrict__ cursor, const int* __restrict__ partials) {
    int i = blockIdx.x * 256 + threadIdx.x;
    if (i < NNG) cursor[i] += partials[blockIdx.x];
}

// ---------------- edge counting-sort by (g,dst) ----------------
// cursor starts as exclusive offsets; ends as segment end positions.
__global__ void k_esort(const int* __restrict__ src, const int* __restrict__ dst,
                        const float* __restrict__ w, const float* __restrict__ dgo_f,
                        int* __restrict__ cursor, int* __restrict__ es,
                        float* __restrict__ ec) {
    int stride = gridDim.x * blockDim.x;
    for (int i = blockIdx.x * blockDim.x + threadIdx.x; i < TOT_E; i += stride) {
        int g = i / N_EDGES;
        int s = src[i], d = dst[i];
        int pos = atomicAdd(&cursor[g * N_NODES + d], 1);
        es[pos] = s;
        ec[pos] = w[i] * dgo_f[g * N_NODES + s];   // premultiply src-side norm
    }
}

// ---------------- gather SpMM: one wave per (g,dst) row, fused norm+ReLU ----------------
__global__ __launch_bounds__(256) void k_gather(
        const float* __restrict__ P, const int* __restrict__ es,
        const float* __restrict__ ec, const int* __restrict__ cursor,
        const int* __restrict__ deg_in, const float* __restrict__ dgi_f,
        float* __restrict__ H) {
    int wid = (int)((blockIdx.x * (unsigned)blockDim.x + threadIdx.x) >> 6);
    int lane = threadIdx.x & 63;
    if (wid >= NNG) return;
    int g = wid / N_NODES;
    int d = wid - g * N_NODES;
    int end = cursor[wid];
    int start = end - deg_in[wid];
    float ax = 0.f, ay = 0.f;
    int e = start;
    for (; e + 1 < end; e += 2) {    // 2-way unroll: two row-loads in flight
        int s0 = es[e], s1 = es[e + 1];
        float c0 = ec[e], c1 = ec[e + 1];
        float2 v0 = *reinterpret_cast<const float2*>(&P[(size_t)s0 * H_FEATS + lane * 2]);
        float2 v1 = *reinterpret_cast<const float2*>(&P[(size_t)s1 * H_FEATS + lane * 2]);
        ax += c0 * v0.x + c1 * v1.x;
        ay += c0 * v0.y + c1 * v1.y;
    }
    if (e < end) {
        int s0 = es[e];
        float c0 = ec[e];
        float2 v0 = *reinterpret_cast<const float2*>(&P[(size_t)s0 * H_FEATS + lane * 2]);
        ax += c0 * v0.x;
        ay += c0 * v0.y;
    }
    float sc = dgi_f[wid];
    float2 r;
    r.x = fmaxf(ax * sc, 0.f);
    r.y = fmaxf(ay * sc, 0.f);
    *reinterpret_cast<float2*>(&H[(size_t)d * CAT + g * H_FEATS + lane * 2]) = r;
}

// ---------------- fp32 tiled GEMM: C[M,N] = act(A[M,K] @ B[K,N] + bias) ----------------
template<bool RELU, bool HASBIAS>
__global__ __launch_bounds__(256, 2) void k_gemm(
        const float* __restrict__ A, const float* __restrict__ B,
        const float* __restrict__ bias, float* __restrict__ C,
        int M, int N, int K) {
    constexpr int BM = 128, BN = 128, BK = 8;
    __shared__ float sA[BK][BM + 4];
    __shared__ float sB[BK][BN + 4];
    const int tid = threadIdx.x;
    const int bm = blockIdx.y * BM, bn = blockIdx.x * BN;
    const int tx = tid & 15, ty = tid >> 4;   // 16x16 threads, 8x8 each
    float acc[8][8] = {};

    for (int k0 = 0; k0 < K; k0 += BK) {
        {
            int r = tid >> 1;
            int c = (tid & 1) * 4;
            int gr = bm + r;
            float4 v = make_float4(0.f, 0.f, 0.f, 0.f);
            if (gr < M)
                v = *reinterpret_cast<const float4*>(&A[(size_t)gr * K + k0 + c]);
            sA[c + 0][r] = v.x; sA[c + 1][r] = v.y;
            sA[c + 2][r] = v.z; sA[c + 3][r] = v.w;
        }
        {
            int col = tid & 127;
            int r0 = tid >> 7;  // 0..1
            #pragma unroll
            for (int r = r0; r < BK; r += 2) {
                float v = 0.f;
                if (bn + col < N) v = B[(size_t)(k0 + r) * N + bn + col];
                sB[r][col] = v;
            }
        }
        __syncthreads();
        #pragma unroll
        for (int k = 0; k < BK; k++) {
            float a[8], b[8];
            #pragma unroll
            for (int i = 0; i < 8; i++) a[i] = sA[k][ty * 8 + i];
            #pragma unroll
            for (int j = 0; j < 8; j++) b[j] = sB[k][tx * 8 + j];
            #pragma unroll
            for (int i = 0; i < 8; i++)
                #pragma unroll
                for (int j = 0; j < 8; j++)
                    acc[i][j] = fmaf(a[i], b[j], acc[i][j]);
        }
        __syncthreads();
    }
    #pragma unroll
    for (int i = 0; i < 8; i++) {
        int gr = bm + ty * 8 + i;
        if (gr >= M) continue;
        #pragma unroll
        for (int j = 0; j < 8; j++) {
            int gc = bn + tx * 8 + j;
            if (gc >= N) continue;
            float v = acc[i][j];
            if (HASBIAS) v += bias[gc];
            if (RELU) v = fmaxf(v, 0.f);
            C[(size_t)gr * N + gc] = v;
        }
    }
}

extern "C" void kernel_launch(void* const* d_in, const int* in_sizes, int n_in,
                              void* d_out, int out_size, void* d_ws, size_t ws_size,
                              hipStream_t stream) {
    const float* in_feat = (const float*)d_in[0];
    const int*   src     = (const int*)d_in[1];
    const int*   dst     = (const int*)d_in[2];
    const float* w       = (const float*)d_in[3];
    const float* W1      = (const float*)d_in[4];
    const float* W2      = (const float*)d_in[5];
    const float* l1w     = (const float*)d_in[6];
    const float* l1b     = (const float*)d_in[7];
    const float* l2w     = (const float*)d_in[8];
    const float* l2b     = (const float*)d_in[9];
    const float* l3w     = (const float*)d_in[10];
    const float* l3b     = (const float*)d_in[11];
    float* out = (float*)d_out;

    float* ws = (float*)d_ws;
    float* P     = ws;                                   // 6.4M floats
    float* H1    = P   + (size_t)N_NODES * H_FEATS;      // 25.6M
    float* H2    = H1  + (size_t)N_NODES * CAT;          // 25.6M
    float* dgo_f = H2  + (size_t)N_NODES * CAT;          // 200K
    float* dgi_f = dgo_f + NNG;                          // 200K
    int*   deg_o = (int*)(dgi_f + NNG);                  // 200K
    int*   deg_i = deg_o + NNG;                          // 200K
    int*   cursor= deg_i + NNG;                          // 200K
    int*   parts = cursor + NNG;                         // 1K
    int*   es    = parts + 1024;                         // 3.2M
    float* ec    = (float*)(es + TOT_E);                 // 3.2M

    const int TPB = 256;
    dim3 blk(TPB);
    const int NB_SCAN = (NNG + 255) / 256;               // 782

    // 1. degree histograms (must re-zero every call)
    hipMemsetAsync(deg_o, 0, 2 * (size_t)NNG * sizeof(int), stream);
    k_deg_i<<<2048, blk, 0, stream>>>(src, deg_o);
    k_deg_i<<<2048, blk, 0, stream>>>(dst, deg_i);
    k_invsqrt_i<<<512, blk, 0, stream>>>(deg_o, dgo_f, 2 * NNG);  // both arrays adjacent

    // 2. exclusive scan deg_i -> cursor
    k_scan1<<<NB_SCAN, blk, 0, stream>>>(deg_i, cursor, parts);
    k_scan2<<<1, 1024, 0, stream>>>(parts, NB_SCAN);
    k_scan3<<<NB_SCAN, blk, 0, stream>>>(cursor, parts);

    // 3. counting-sort edges by (g,dst); cursor becomes segment ends
    k_esort<<<4096, blk, 0, stream>>>(src, dst, w, dgo_f, cursor, es, ec);

    dim3 gP(1, (N_NODES + 127) / 128);       // N=128
    dim3 gC((CAT + 127) / 128, (N_NODES + 127) / 128);
    dim3 gO(1, (N_NODES + 127) / 128);       // N=40
    const int GATHER_BLKS = (NNG * 64 + TPB - 1) / TPB;  // 50000

    // 4. P = in_feat @ W1
    k_gemm<false, false><<<gP, blk, 0, stream>>>(in_feat, W1, nullptr, P,
                                                 N_NODES, H_FEATS, IN_FEATS);
    // 5. conv1 gather into H1 (norm + ReLU fused, no memset needed)
    k_gather<<<GATHER_BLKS, blk, 0, stream>>>(P, es, ec, cursor, deg_i, dgi_f, H1);

    // 6. H2 = relu(H1 @ l1w + l1b)
    k_gemm<true, true><<<gC, blk, 0, stream>>>(H1, l1w, l1b, H2, N_NODES, CAT, CAT);
    // 7. H1 = relu(H2 @ l2w + l2b)
    k_gemm<true, true><<<gC, blk, 0, stream>>>(H2, l2w, l2b, H1, N_NODES, CAT, CAT);

    // 8. P = H1 @ W2
    k_gemm<false, false><<<gP, blk, 0, stream>>>(H1, W2, nullptr, P,
                                                 N_NODES, H_FEATS, CAT);
    // 9. conv2 gather into H2
    k_gather<<<GATHER_BLKS, blk, 0, stream>>>(P, es, ec, cursor, deg_i, dgi_f, H2);

    // 10. out = H2 @ l3w + l3b
    k_gemm<false, true><<<gO, blk, 0, stream>>>(H2, l3w, l3b, out,
                                                N_NODES, NUM_CLS, CAT);
}

// Round 3
// 1794.941 us; speedup vs baseline: 6.9782x; 1.2503x over previous
//
#include <hip/hip_runtime.h>

#define N_NODES  50000
#define G_NUM    4
#define N_EDGES  800000
#define IN_FEATS 256
#define H_FEATS  128
#define NUM_CLS  40
#define CAT      512   // H_FEATS * G_NUM
#define NNG      (G_NUM * N_NODES)   // 200000
#define TOT_E    (G_NUM * N_EDGES)   // 3200000

typedef unsigned short u16;
typedef __attribute__((ext_vector_type(8))) short s16x8;
typedef __attribute__((ext_vector_type(4))) float f32x4;

// ---- bf16 split helpers ----
__device__ __forceinline__ u16 f2bf(float x) {
    unsigned u = __float_as_uint(x);
    unsigned r = (u + 0x7FFFu + ((u >> 16) & 1u)) >> 16;
    return (u16)r;
}
__device__ __forceinline__ float bf2f(u16 h) {
    return __uint_as_float(((unsigned)h) << 16);
}

// ---------------- degree accumulation (int) ----------------
__global__ void k_deg_i(const int* __restrict__ idx, int* __restrict__ deg) {
    int stride = gridDim.x * blockDim.x;
    for (int i = blockIdx.x * blockDim.x + threadIdx.x; i < TOT_E; i += stride) {
        int g = i / N_EDGES;
        atomicAdd(&deg[g * N_NODES + idx[i]], 1);
    }
}

__global__ void k_invsqrt_i(const int* __restrict__ d, float* __restrict__ f, int n) {
    int stride = gridDim.x * blockDim.x;
    for (int i = blockIdx.x * blockDim.x + threadIdx.x; i < n; i += stride)
        f[i] = rsqrtf(fmaxf((float)d[i], 1.0f));
}

// ---------------- exclusive scan of deg_in ----------------
__global__ void k_scan1(const int* __restrict__ deg, int* __restrict__ cursor,
                        int* __restrict__ partials) {
    __shared__ int s[256];
    int i = blockIdx.x * 256 + threadIdx.x;
    int v = (i < NNG) ? deg[i] : 0;
    s[threadIdx.x] = v;
    __syncthreads();
    for (int off = 1; off < 256; off <<= 1) {
        int t = (threadIdx.x >= off) ? s[threadIdx.x - off] : 0;
        __syncthreads();
        s[threadIdx.x] += t;
        __syncthreads();
    }
    if (i < NNG) cursor[i] = s[threadIdx.x] - v;
    if (threadIdx.x == 255) partials[blockIdx.x] = s[255];
}
__global__ void k_scan2(int* __restrict__ partials, int n) {
    __shared__ int s[1024];
    int v = (threadIdx.x < n) ? partials[threadIdx.x] : 0;
    s[threadIdx.x] = v;
    __syncthreads();
    for (int off = 1; off < 1024; off <<= 1) {
        int t = (threadIdx.x >= off) ? s[threadIdx.x - off] : 0;
        __syncthreads();
        s[threadIdx.x] += t;
        __syncthreads();
    }
    if (threadIdx.x < n) partials[threadIdx.x] = s[threadIdx.x] - v;
}
__global__ void k_scan3(int* __restrict__ cursor, const int* __restrict__ partials) {
    int i = blockIdx.x * 256 + threadIdx.x;
    if (i < NNG) cursor[i] += partials[blockIdx.x];
}

// ---------------- edge counting-sort by (g,dst) ----------------
__global__ void k_esort(const int* __restrict__ src, const int* __restrict__ dst,
                        const float* __restrict__ w, const float* __restrict__ dgo_f,
                        int* __restrict__ cursor, int* __restrict__ es,
                        float* __restrict__ ec) {
    int stride = gridDim.x * blockDim.x;
    for (int i = blockIdx.x * blockDim.x + threadIdx.x; i < TOT_E; i += stride) {
        int g = i / N_EDGES;
        int s = src[i], d = dst[i];
        int pos = atomicAdd(&cursor[g * N_NODES + d], 1);
        es[pos] = s;
        ec[pos] = w[i] * dgo_f[g * N_NODES + s];
    }
}

// ---------------- gather SpMM: one wave per (g,dst) row ----------------
// SPLIT=1: write bf16 (hi,lo) pair arrays; SPLIT=0: write fp32 H
template<int SPLIT>
__global__ __launch_bounds__(256) void k_gather(
        const float* __restrict__ P, const int* __restrict__ es,
        const float* __restrict__ ec, const int* __restrict__ cursor,
        const int* __restrict__ deg_in, const float* __restrict__ dgi_f,
        float* __restrict__ H, u16* __restrict__ Sh, u16* __restrict__ Sl) {
    int wid = (int)((blockIdx.x * (unsigned)blockDim.x + threadIdx.x) >> 6);
    int lane = threadIdx.x & 63;
    if (wid >= NNG) return;
    int g = wid / N_NODES;
    int d = wid - g * N_NODES;
    int end = cursor[wid];
    int start = end - deg_in[wid];
    float ax = 0.f, ay = 0.f;
    int e = start;
    for (; e + 1 < end; e += 2) {
        int s0 = es[e], s1 = es[e + 1];
        float c0 = ec[e], c1 = ec[e + 1];
        float2 v0 = *reinterpret_cast<const float2*>(&P[(size_t)s0 * H_FEATS + lane * 2]);
        float2 v1 = *reinterpret_cast<const float2*>(&P[(size_t)s1 * H_FEATS + lane * 2]);
        ax += c0 * v0.x + c1 * v1.x;
        ay += c0 * v0.y + c1 * v1.y;
    }
    if (e < end) {
        int s0 = es[e];
        float c0 = ec[e];
        float2 v0 = *reinterpret_cast<const float2*>(&P[(size_t)s0 * H_FEATS + lane * 2]);
        ax += c0 * v0.x;
        ay += c0 * v0.y;
    }
    float sc = dgi_f[wid];
    float rx = fmaxf(ax * sc, 0.f);
    float ry = fmaxf(ay * sc, 0.f);
    size_t base = (size_t)d * CAT + g * H_FEATS + lane * 2;
    if (SPLIT) {
        u16 hx = f2bf(rx), hy = f2bf(ry);
        u16 lx = f2bf(rx - bf2f(hx)), ly = f2bf(ry - bf2f(hy));
        ushort2 hv; hv.x = hx; hv.y = hy;
        ushort2 lv; lv.x = lx; lv.y = ly;
        *reinterpret_cast<ushort2*>(&Sh[base]) = hv;
        *reinterpret_cast<ushort2*>(&Sl[base]) = lv;
    } else {
        float2 r; r.x = rx; r.y = ry;
        *reinterpret_cast<float2*>(&H[base]) = r;
    }
}

// ---------------- weight transpose + bf16 split: W[K][N] -> Th/Tl[N][K] ----------------
__global__ void k_splitw(const float* __restrict__ W, u16* __restrict__ Th,
                         u16* __restrict__ Tl, int K, int N) {
    int i = blockIdx.x * 256 + threadIdx.x;
    if (i >= K * N) return;
    int k = i / N, n = i - k * N;
    float x = W[i];
    u16 h = f2bf(x);
    Th[(size_t)n * K + k] = h;
    Tl[(size_t)n * K + k] = f2bf(x - bf2f(h));
}

// ---------------- bf16x3 split-precision MFMA GEMM ----------------
// C[M][N] = act(A[M][K] @ Bt[N][K]^T + bias);  A,Bt given as bf16 (hi,lo) pairs.
// 128x128 tile, BK=32, 4 waves (2x2), each wave 64x64 = 4x4 frags of 16x16x32.
template<bool RELU, bool SPLIT_OUT, bool HASBIAS>
__global__ __launch_bounds__(256, 1) void k_mfma(
        const u16* __restrict__ Ah, const u16* __restrict__ Al,
        const u16* __restrict__ Bth, const u16* __restrict__ Btl,
        const float* __restrict__ bias,
        float* __restrict__ Cf, u16* __restrict__ Ch, u16* __restrict__ Cl,
        int M, int N, int K) {
    __shared__ s16x8 sA[2][4][128];   // [hi/lo][k8][row]  16 KB
    __shared__ s16x8 sB[2][4][128];   // [hi/lo][k8][col]  16 KB
    const int tid = threadIdx.x;
    const int lane = tid & 63;
    const int wave = tid >> 6;
    const int wr = wave >> 1, wc = wave & 1;
    const int l15 = lane & 15, l4 = lane >> 4;
    const int bm = blockIdx.y * 128, bn = blockIdx.x * 128;

    const int sidx = tid & 127;       // staging row/col
    const int sw = tid >> 7;          // 0 = hi, 1 = lo
    const u16* As = sw ? Al : Ah;
    const u16* Bs = sw ? Btl : Bth;
    const int arow = bm + sidx;
    const bool aok = arow < M;
    const size_t abase = (size_t)arow * K;
    const size_t bbase = (size_t)(bn + sidx) * K;   // N is a multiple of 128

    f32x4 acc[4][4];
    #pragma unroll
    for (int m = 0; m < 4; m++)
        #pragma unroll
        for (int n = 0; n < 4; n++)
            acc[m][n] = (f32x4){0.f, 0.f, 0.f, 0.f};

    const s16x8 vzero = {0, 0, 0, 0, 0, 0, 0, 0};

    for (int k0 = 0; k0 < K; k0 += 32) {
        s16x8 av[4], bv[4];
        #pragma unroll
        for (int k8 = 0; k8 < 4; k8++) {
            av[k8] = aok ? *reinterpret_cast<const s16x8*>(&As[abase + k0 + k8 * 8]) : vzero;
            bv[k8] = *reinterpret_cast<const s16x8*>(&Bs[bbase + k0 + k8 * 8]);
        }
        __syncthreads();              // previous compute done reading LDS
        #pragma unroll
        for (int k8 = 0; k8 < 4; k8++) {
            sA[sw][k8][sidx] = av[k8];
            sB[sw][k8][sidx] = bv[k8];
        }
        __syncthreads();
        s16x8 fah[4], fal[4], fbh[4], fbl[4];
        #pragma unroll
        for (int m = 0; m < 4; m++) {
            fah[m] = sA[0][l4][wr * 64 + m * 16 + l15];
            fal[m] = sA[1][l4][wr * 64 + m * 16 + l15];
        }
        #pragma unroll
        for (int n = 0; n < 4; n++) {
            fbh[n] = sB[0][l4][wc * 64 + n * 16 + l15];
            fbl[n] = sB[1][l4][wc * 64 + n * 16 + l15];
        }
        #pragma unroll
        for (int m = 0; m < 4; m++)
            #pragma unroll
            for (int n = 0; n < 4; n++) {
                acc[m][n] = __builtin_amdgcn_mfma_f32_16x16x32_bf16(fah[m], fbh[n], acc[m][n], 0, 0, 0);
                acc[m][n] = __builtin_amdgcn_mfma_f32_16x16x32_bf16(fah[m], fbl[n], acc[m][n], 0, 0, 0);
                acc[m][n] = __builtin_amdgcn_mfma_f32_16x16x32_bf16(fal[m], fbh[n], acc[m][n], 0, 0, 0);
            }
    }

    // epilogue: D col = lane&15, row = (lane>>4)*4 + r   [m89 layout]
    #pragma unroll
    for (int n = 0; n < 4; n++) {
        int col = bn + wc * 64 + n * 16 + l15;
        float bs = HASBIAS ? bias[col] : 0.0f;
        #pragma unroll
        for (int m = 0; m < 4; m++) {
            #pragma unroll
            for (int r = 0; r < 4; r++) {
                int row = bm + wr * 64 + m * 16 + l4 * 4 + r;
                if (row < M) {
                    float x = acc[m][n][r] + bs;
                    if (RELU) x = fmaxf(x, 0.f);
                    if (SPLIT_OUT) {
                        u16 h = f2bf(x);
                        Ch[(size_t)row * N + col] = h;
                        Cl[(size_t)row * N + col] = f2bf(x - bf2f(h));
                    } else {
                        Cf[(size_t)row * N + col] = x;
                    }
                }
            }
        }
    }
}

// ---------------- fp32 tiled GEMM (kept for the two small ones) ----------------
template<bool RELU, bool HASBIAS>
__global__ __launch_bounds__(256, 2) void k_gemm(
        const float* __restrict__ A, const float* __restrict__ B,
        const float* __restrict__ bias, float* __restrict__ C,
        int M, int N, int K) {
    constexpr int BM = 128, BN = 128, BK = 8;
    __shared__ float sA[BK][BM + 4];
    __shared__ float sB[BK][BN + 4];
    const int tid = threadIdx.x;
    const int bm = blockIdx.y * BM, bn = blockIdx.x * BN;
    const int tx = tid & 15, ty = tid >> 4;
    float acc[8][8] = {};

    for (int k0 = 0; k0 < K; k0 += BK) {
        {
            int r = tid >> 1;
            int c = (tid & 1) * 4;
            int gr = bm + r;
            float4 v = make_float4(0.f, 0.f, 0.f, 0.f);
            if (gr < M)
                v = *reinterpret_cast<const float4*>(&A[(size_t)gr * K + k0 + c]);
            sA[c + 0][r] = v.x; sA[c + 1][r] = v.y;
            sA[c + 2][r] = v.z; sA[c + 3][r] = v.w;
        }
        {
            int col = tid & 127;
            int r0 = tid >> 7;
            #pragma unroll
            for (int r = r0; r < BK; r += 2) {
                float v = 0.f;
                if (bn + col < N) v = B[(size_t)(k0 + r) * N + bn + col];
                sB[r][col] = v;
            }
        }
        __syncthreads();
        #pragma unroll
        for (int k = 0; k < BK; k++) {
            float a[8], b[8];
            #pragma unroll
            for (int i = 0; i < 8; i++) a[i] = sA[k][ty * 8 + i];
            #pragma unroll
            for (int j = 0; j < 8; j++) b[j] = sB[k][tx * 8 + j];
            #pragma unroll
            for (int i = 0; i < 8; i++)
                #pragma unroll
                for (int j = 0; j < 8; j++)
                    acc[i][j] = fmaf(a[i], b[j], acc[i][j]);
        }
        __syncthreads();
    }
    #pragma unroll
    for (int i = 0; i < 8; i++) {
        int gr = bm + ty * 8 + i;
        if (gr >= M) continue;
        #pragma unroll
        for (int j = 0; j < 8; j++) {
            int gc = bn + tx * 8 + j;
            if (gc >= N) continue;
            float v = acc[i][j];
            if (HASBIAS) v += bias[gc];
            if (RELU) v = fmaxf(v, 0.f);
            C[(size_t)gr * N + gc] = v;
        }
    }
}

extern "C" void kernel_launch(void* const* d_in, const int* in_sizes, int n_in,
                              void* d_out, int out_size, void* d_ws, size_t ws_size,
                              hipStream_t stream) {
    const float* in_feat = (const float*)d_in[0];
    const int*   src     = (const int*)d_in[1];
    const int*   dst     = (const int*)d_in[2];
    const float* w       = (const float*)d_in[3];
    const float* W1      = (const float*)d_in[4];
    const float* W2      = (const float*)d_in[5];
    const float* l1w     = (const float*)d_in[6];
    const float* l1b     = (const float*)d_in[7];
    const float* l2w     = (const float*)d_in[8];
    const float* l2b     = (const float*)d_in[9];
    const float* l3w     = (const float*)d_in[10];
    const float* l3b     = (const float*)d_in[11];
    float* out = (float*)d_out;

    // ---- workspace carve (bytes) ----
    char* base = (char*)d_ws;
    float* P    = (float*)base;  base += (size_t)N_NODES * H_FEATS * 4;      // 25.6 MB
    u16*   S1h  = (u16*)base;    base += (size_t)N_NODES * CAT * 2;          // 51.2 MB
    u16*   S1l  = (u16*)base;    base += (size_t)N_NODES * CAT * 2;
    u16*   S2h  = (u16*)base;    base += (size_t)N_NODES * CAT * 2;          // S2h+S2l also
    u16*   S2l  = (u16*)base;    base += (size_t)N_NODES * CAT * 2;          //  reused as H2f
    float* H2f  = (float*)S2h;                                               // 102.4 MB alias
    u16*   l1th = (u16*)base;    base += (size_t)CAT * CAT * 2;
    u16*   l1tl = (u16*)base;    base += (size_t)CAT * CAT * 2;
    u16*   l2th = (u16*)base;    base += (size_t)CAT * CAT * 2;
    u16*   l2tl = (u16*)base;    base += (size_t)CAT * CAT * 2;
    u16*   w2th = (u16*)base;    base += (size_t)CAT * H_FEATS * 2;
    u16*   w2tl = (u16*)base;    base += (size_t)CAT * H_FEATS * 2;
    float* dgo_f = (float*)base; base += (size_t)NNG * 4;
    float* dgi_f = (float*)base; base += (size_t)NNG * 4;
    int*   deg_o = (int*)base;   base += (size_t)NNG * 4;
    int*   deg_i = (int*)base;   base += (size_t)NNG * 4;
    int*   cursor= (int*)base;   base += (size_t)NNG * 4;
    int*   parts = (int*)base;   base += 4096;
    int*   es    = (int*)base;   base += (size_t)TOT_E * 4;
    float* ec    = (float*)base; base += (size_t)TOT_E * 4;

    const int TPB = 256;
    dim3 blk(TPB);
    const int NB_SCAN = (NNG + 255) / 256;

    // 1. degree histograms
    hipMemsetAsync(deg_o, 0, 2 * (size_t)NNG * sizeof(int), stream);
    k_deg_i<<<2048, blk, 0, stream>>>(src, deg_o);
    k_deg_i<<<2048, blk, 0, stream>>>(dst, deg_i);
    k_invsqrt_i<<<512, blk, 0, stream>>>(deg_o, dgo_f, 2 * NNG);  // deg_o,deg_i adjacent

    // 2. scan + 3. sort
    k_scan1<<<NB_SCAN, blk, 0, stream>>>(deg_i, cursor, parts);
    k_scan2<<<1, 1024, 0, stream>>>(parts, NB_SCAN);
    k_scan3<<<NB_SCAN, blk, 0, stream>>>(cursor, parts);
    k_esort<<<4096, blk, 0, stream>>>(src, dst, w, dgo_f, cursor, es, ec);

    // 4. weight transpose+split
    k_splitw<<<(CAT * CAT + 255) / 256, blk, 0, stream>>>(l1w, l1th, l1tl, CAT, CAT);
    k_splitw<<<(CAT * CAT + 255) / 256, blk, 0, stream>>>(l2w, l2th, l2tl, CAT, CAT);
    k_splitw<<<(CAT * H_FEATS + 255) / 256, blk, 0, stream>>>(W2, w2th, w2tl, CAT, H_FEATS);

    dim3 gP(1, (N_NODES + 127) / 128);
    dim3 gO(1, (N_NODES + 127) / 128);
    dim3 gM4(4, (N_NODES + 127) / 128);
    dim3 gM1(1, (N_NODES + 127) / 128);
    const int GATHER_BLKS = (NNG * 64 + TPB - 1) / TPB;

    // 5. P = in_feat @ W1 (fp32 vector)
    k_gemm<false, false><<<gP, blk, 0, stream>>>(in_feat, W1, nullptr, P,
                                                 N_NODES, H_FEATS, IN_FEATS);
    // 6. conv1 gather -> split bf16 S1
    k_gather<1><<<GATHER_BLKS, blk, 0, stream>>>(P, es, ec, cursor, deg_i, dgi_f,
                                                 nullptr, S1h, S1l);
    // 7. S2 = relu(S1 @ l1w + l1b)   (bf16x3 MFMA, split out)
    k_mfma<true, true, true><<<gM4, blk, 0, stream>>>(
        S1h, S1l, l1th, l1tl, l1b, nullptr, S2h, S2l, N_NODES, CAT, CAT);
    // 8. S1 = relu(S2 @ l2w + l2b)
    k_mfma<true, true, true><<<gM4, blk, 0, stream>>>(
        S2h, S2l, l2th, l2tl, l2b, nullptr, S1h, S1l, N_NODES, CAT, CAT);
    // 9. P = S1 @ W2  (fp32 out)
    k_mfma<false, false, false><<<gM1, blk, 0, stream>>>(
        S1h, S1l, w2th, w2tl, nullptr, P, nullptr, nullptr, N_NODES, H_FEATS, CAT);
    // 10. conv2 gather -> H2f fp32 (overwrites S2 region)
    k_gather<0><<<GATHER_BLKS, blk, 0, stream>>>(P, es, ec, cursor, deg_i, dgi_f,
                                                 H2f, nullptr, nullptr);
    // 11. out = H2f @ l3w + l3b (fp32 vector)
    k_gemm<false, true><<<gO, blk, 0, stream>>>(H2f, l3w, l3b, out,
                                                N_NODES, NUM_CLS, CAT);
}

// Round 4
// 1608.734 us; speedup vs baseline: 7.7859x; 1.1157x over previous
//
#include <hip/hip_runtime.h>

#define N_NODES  50000
#define G_NUM    4
#define N_EDGES  800000
#define IN_FEATS 256
#define H_FEATS  128
#define NUM_CLS  40
#define CAT      512   // H_FEATS * G_NUM
#define NNG      (G_NUM * N_NODES)   // 200000
#define TOT_E    (G_NUM * N_EDGES)   // 3200000

typedef unsigned short u16;
typedef __attribute__((ext_vector_type(8))) short s16x8;
typedef __attribute__((ext_vector_type(4))) float f32x4;

// ---- bf16 split helpers ----
__device__ __forceinline__ u16 f2bf(float x) {
    unsigned u = __float_as_uint(x);
    unsigned r = (u + 0x7FFFu + ((u >> 16) & 1u)) >> 16;
    return (u16)r;
}
__device__ __forceinline__ float bf2f(u16 h) {
    return __uint_as_float(((unsigned)h) << 16);
}

// ---------------- degree accumulation (int) ----------------
__global__ void k_deg_i(const int* __restrict__ idx, int* __restrict__ deg) {
    int stride = gridDim.x * blockDim.x;
    for (int i = blockIdx.x * blockDim.x + threadIdx.x; i < TOT_E; i += stride) {
        int g = i / N_EDGES;
        atomicAdd(&deg[g * N_NODES + idx[i]], 1);
    }
}

__global__ void k_invsqrt_i(const int* __restrict__ d, float* __restrict__ f, int n) {
    int stride = gridDim.x * blockDim.x;
    for (int i = blockIdx.x * blockDim.x + threadIdx.x; i < n; i += stride)
        f[i] = rsqrtf(fmaxf((float)d[i], 1.0f));
}

// ---------------- exclusive scan of deg_in ----------------
__global__ void k_scan1(const int* __restrict__ deg, int* __restrict__ cursor,
                        int* __restrict__ partials) {
    __shared__ int s[256];
    int i = blockIdx.x * 256 + threadIdx.x;
    int v = (i < NNG) ? deg[i] : 0;
    s[threadIdx.x] = v;
    __syncthreads();
    for (int off = 1; off < 256; off <<= 1) {
        int t = (threadIdx.x >= off) ? s[threadIdx.x - off] : 0;
        __syncthreads();
        s[threadIdx.x] += t;
        __syncthreads();
    }
    if (i < NNG) cursor[i] = s[threadIdx.x] - v;
    if (threadIdx.x == 255) partials[blockIdx.x] = s[255];
}
__global__ void k_scan2(int* __restrict__ partials, int n) {
    __shared__ int s[1024];
    int v = (threadIdx.x < n) ? partials[threadIdx.x] : 0;
    s[threadIdx.x] = v;
    __syncthreads();
    for (int off = 1; off < 1024; off <<= 1) {
        int t = (threadIdx.x >= off) ? s[threadIdx.x - off] : 0;
        __syncthreads();
        s[threadIdx.x] += t;
        __syncthreads();
    }
    if (threadIdx.x < n) partials[threadIdx.x] = s[threadIdx.x] - v;
}
__global__ void k_scan3(int* __restrict__ cursor, const int* __restrict__ partials) {
    int i = blockIdx.x * 256 + threadIdx.x;
    if (i < NNG) cursor[i] += partials[blockIdx.x];
}

// ---------------- edge counting-sort by (g,dst) ----------------
__global__ void k_esort(const int* __restrict__ src, const int* __restrict__ dst,
                        const float* __restrict__ w, const float* __restrict__ dgo_f,
                        int* __restrict__ cursor, int* __restrict__ es,
                        float* __restrict__ ec) {
    int stride = gridDim.x * blockDim.x;
    for (int i = blockIdx.x * blockDim.x + threadIdx.x; i < TOT_E; i += stride) {
        int g = i / N_EDGES;
        int s = src[i], d = dst[i];
        int pos = atomicAdd(&cursor[g * N_NODES + d], 1);
        es[pos] = s;
        ec[pos] = w[i] * dgo_f[g * N_NODES + s];
    }
}

// ---------------- gather SpMM: one wave per (g,dst) row ----------------
template<int SPLIT>
__global__ __launch_bounds__(256) void k_gather(
        const float* __restrict__ P, const int* __restrict__ es,
        const float* __restrict__ ec, const int* __restrict__ cursor,
        const int* __restrict__ deg_in, const float* __restrict__ dgi_f,
        float* __restrict__ H, u16* __restrict__ Sh, u16* __restrict__ Sl) {
    int wid = (int)((blockIdx.x * (unsigned)blockDim.x + threadIdx.x) >> 6);
    int lane = threadIdx.x & 63;
    if (wid >= NNG) return;
    int g = wid / N_NODES;
    int d = wid - g * N_NODES;
    int end = cursor[wid];
    int start = end - deg_in[wid];
    float ax = 0.f, ay = 0.f;
    int e = start;
    for (; e + 1 < end; e += 2) {
        int s0 = es[e], s1 = es[e + 1];
        float c0 = ec[e], c1 = ec[e + 1];
        float2 v0 = *reinterpret_cast<const float2*>(&P[(size_t)s0 * H_FEATS + lane * 2]);
        float2 v1 = *reinterpret_cast<const float2*>(&P[(size_t)s1 * H_FEATS + lane * 2]);
        ax += c0 * v0.x + c1 * v1.x;
        ay += c0 * v0.y + c1 * v1.y;
    }
    if (e < end) {
        int s0 = es[e];
        float c0 = ec[e];
        float2 v0 = *reinterpret_cast<const float2*>(&P[(size_t)s0 * H_FEATS + lane * 2]);
        ax += c0 * v0.x;
        ay += c0 * v0.y;
    }
    float sc = dgi_f[wid];
    float rx = fmaxf(ax * sc, 0.f);
    float ry = fmaxf(ay * sc, 0.f);
    size_t base = (size_t)d * CAT + g * H_FEATS + lane * 2;
    if (SPLIT) {
        u16 hx = f2bf(rx), hy = f2bf(ry);
        u16 lx = f2bf(rx - bf2f(hx)), ly = f2bf(ry - bf2f(hy));
        ushort2 hv; hv.x = hx; hv.y = hy;
        ushort2 lv; lv.x = lx; lv.y = ly;
        *reinterpret_cast<ushort2*>(&Sh[base]) = hv;
        *reinterpret_cast<ushort2*>(&Sl[base]) = lv;
    } else {
        float2 r; r.x = rx; r.y = ry;
        *reinterpret_cast<float2*>(&H[base]) = r;
    }
}

// ---------------- weight transpose + bf16 split: W[K][N] -> Th/Tl[N][K] ----------------
__global__ void k_splitw(const float* __restrict__ W, u16* __restrict__ Th,
                         u16* __restrict__ Tl, int K, int N) {
    int i = blockIdx.x * 256 + threadIdx.x;
    if (i >= K * N) return;
    int k = i / N, n = i - k * N;
    float x = W[i];
    u16 h = f2bf(x);
    Th[(size_t)n * K + k] = h;
    Tl[(size_t)n * K + k] = f2bf(x - bf2f(h));
}

// ---------------- activation split: X[n] fp32 -> Xh/Xl bf16 (same layout) ----------------
__global__ void k_splita(const float* __restrict__ X, u16* __restrict__ Xh,
                         u16* __restrict__ Xl, int n4) {
    int stride = gridDim.x * blockDim.x;
    for (int i = blockIdx.x * blockDim.x + threadIdx.x; i < n4; i += stride) {
        float4 v = reinterpret_cast<const float4*>(X)[i];
        ushort4 h, l;
        h.x = f2bf(v.x); l.x = f2bf(v.x - bf2f(h.x));
        h.y = f2bf(v.y); l.y = f2bf(v.y - bf2f(h.y));
        h.z = f2bf(v.z); l.z = f2bf(v.z - bf2f(h.z));
        h.w = f2bf(v.w); l.w = f2bf(v.w - bf2f(h.w));
        reinterpret_cast<ushort4*>(Xh)[i] = h;
        reinterpret_cast<ushort4*>(Xl)[i] = l;
    }
}

// ---------------- bf16x3 split-precision MFMA GEMM, reg-prefetch pipelined ----------------
// C[M][N] = act(A[M][K] @ Bt[N][K]^T + bias). 128x128 tile, BK=32, 4 waves 2x2.
// 1-D grid (nbx*nby blocks) with bijective XCD swizzle grouping column-tiles
// of the same A row-panel onto one XCD (L2 reuse of A).
template<bool RELU, bool SPLIT_OUT, bool HASBIAS>
__global__ __launch_bounds__(256, 1) void k_mfma(
        const u16* __restrict__ Ah, const u16* __restrict__ Al,
        const u16* __restrict__ Bth, const u16* __restrict__ Btl,
        const float* __restrict__ bias,
        float* __restrict__ Cf, u16* __restrict__ Ch, u16* __restrict__ Cl,
        int M, int N, int K, int nbx) {
    __shared__ s16x8 sA[2][4][128];   // [hi/lo][k8][row] 16 KB
    __shared__ s16x8 sB[2][4][128];   // [hi/lo][k8][col] 16 KB

    // bijective XCD swizzle (m204): contiguous logical range per XCD
    int nwg = gridDim.x;
    int q = nwg >> 3, r = nwg & 7;
    int xcd = blockIdx.x & 7, rest = blockIdx.x >> 3;
    int lg = (xcd < r ? xcd * (q + 1) : r * (q + 1) + (xcd - r) * q) + rest;
    int bx = lg % nbx, by = lg / nbx;

    const int tid = threadIdx.x;
    const int lane = tid & 63;
    const int wave = tid >> 6;
    const int wr = wave >> 1, wc = wave & 1;
    const int l15 = lane & 15, l4 = lane >> 4;
    const int bm = by * 128, bn = bx * 128;

    const int sidx = tid & 127;       // staging row/col
    const int sw = tid >> 7;          // 0 = hi, 1 = lo
    const u16* As = sw ? Al : Ah;
    const u16* Bs = sw ? Btl : Bth;
    const int arow = bm + sidx;
    const bool aok = arow < M;
    const bool bok = (bn + sidx) < N;
    const size_t abase = (size_t)arow * K;
    const size_t bbase = (size_t)(bn + sidx) * K;

    f32x4 acc[4][4];
    #pragma unroll
    for (int m = 0; m < 4; m++)
        #pragma unroll
        for (int n = 0; n < 4; n++)
            acc[m][n] = (f32x4){0.f, 0.f, 0.f, 0.f};

    const s16x8 vzero = {0, 0, 0, 0, 0, 0, 0, 0};
    s16x8 av[4], bv[4];
    #pragma unroll
    for (int k8 = 0; k8 < 4; k8++) {
        av[k8] = aok ? *reinterpret_cast<const s16x8*>(&As[abase + k8 * 8]) : vzero;
        bv[k8] = bok ? *reinterpret_cast<const s16x8*>(&Bs[bbase + k8 * 8]) : vzero;
    }

    for (int k0 = 0; k0 < K; k0 += 32) {
        __syncthreads();              // previous compute done reading LDS
        #pragma unroll
        for (int k8 = 0; k8 < 4; k8++) {
            sA[sw][k8][sidx] = av[k8];     // vmcnt wait lands here (hidden by prev MFMAs)
            sB[sw][k8][sidx] = bv[k8];
        }
        __syncthreads();
        int kn = k0 + 32;
        if (kn < K) {                 // issue next tile's loads BEFORE the MFMA cluster
            #pragma unroll
            for (int k8 = 0; k8 < 4; k8++) {
                av[k8] = aok ? *reinterpret_cast<const s16x8*>(&As[abase + kn + k8 * 8]) : vzero;
                bv[k8] = bok ? *reinterpret_cast<const s16x8*>(&Bs[bbase + kn + k8 * 8]) : vzero;
            }
        }
        s16x8 fah[4], fal[4], fbh[4], fbl[4];
        #pragma unroll
        for (int m = 0; m < 4; m++) {
            fah[m] = sA[0][l4][wr * 64 + m * 16 + l15];
            fal[m] = sA[1][l4][wr * 64 + m * 16 + l15];
        }
        #pragma unroll
        for (int n = 0; n < 4; n++) {
            fbh[n] = sB[0][l4][wc * 64 + n * 16 + l15];
            fbl[n] = sB[1][l4][wc * 64 + n * 16 + l15];
        }
        #pragma unroll
        for (int m = 0; m < 4; m++)
            #pragma unroll
            for (int n = 0; n < 4; n++) {
                acc[m][n] = __builtin_amdgcn_mfma_f32_16x16x32_bf16(fah[m], fbh[n], acc[m][n], 0, 0, 0);
                acc[m][n] = __builtin_amdgcn_mfma_f32_16x16x32_bf16(fah[m], fbl[n], acc[m][n], 0, 0, 0);
                acc[m][n] = __builtin_amdgcn_mfma_f32_16x16x32_bf16(fal[m], fbh[n], acc[m][n], 0, 0, 0);
            }
    }

    // epilogue: D col = lane&15, row = (lane>>4)*4 + r   [m89 layout]
    #pragma unroll
    for (int n = 0; n < 4; n++) {
        int col = bn + wc * 64 + n * 16 + l15;
        if (col >= N) continue;
        float bs = HASBIAS ? bias[col] : 0.0f;
        #pragma unroll
        for (int m = 0; m < 4; m++) {
            #pragma unroll
            for (int r = 0; r < 4; r++) {
                int row = bm + wr * 64 + m * 16 + l4 * 4 + r;
                if (row < M) {
                    float x = acc[m][n][r] + bs;
                    if (RELU) x = fmaxf(x, 0.f);
                    if (SPLIT_OUT) {
                        u16 h = f2bf(x);
                        Ch[(size_t)row * N + col] = h;
                        Cl[(size_t)row * N + col] = f2bf(x - bf2f(h));
                    } else {
                        Cf[(size_t)row * N + col] = x;
                    }
                }
            }
        }
    }
}

extern "C" void kernel_launch(void* const* d_in, const int* in_sizes, int n_in,
                              void* d_out, int out_size, void* d_ws, size_t ws_size,
                              hipStream_t stream) {
    const float* in_feat = (const float*)d_in[0];
    const int*   src     = (const int*)d_in[1];
    const int*   dst     = (const int*)d_in[2];
    const float* w       = (const float*)d_in[3];
    const float* W1      = (const float*)d_in[4];
    const float* W2      = (const float*)d_in[5];
    const float* l1w     = (const float*)d_in[6];
    const float* l1b     = (const float*)d_in[7];
    const float* l2w     = (const float*)d_in[8];
    const float* l2b     = (const float*)d_in[9];
    const float* l3w     = (const float*)d_in[10];
    const float* l3b     = (const float*)d_in[11];
    float* out = (float*)d_out;

    // ---- workspace carve ----
    char* base = (char*)d_ws;
    float* P    = (float*)base;  base += (size_t)N_NODES * H_FEATS * 4;      // 25.6 MB
    u16*   S1h  = (u16*)base;    base += (size_t)N_NODES * CAT * 2;          // 51.2 MB
    u16*   S1l  = (u16*)base;    base += (size_t)N_NODES * CAT * 2;
    u16*   S2h  = (u16*)base;    base += (size_t)N_NODES * CAT * 2;
    u16*   S2l  = (u16*)base;    base += (size_t)N_NODES * CAT * 2;
    // S0 (split in_feat, 50000x256) aliases S2: S0 dead before S2 first written
    u16*   S0h  = S2h;
    u16*   S0l  = S2h + (size_t)N_NODES * IN_FEATS;
    u16*   w1th = (u16*)base;    base += (size_t)IN_FEATS * H_FEATS * 2;
    u16*   w1tl = (u16*)base;    base += (size_t)IN_FEATS * H_FEATS * 2;
    u16*   l1th = (u16*)base;    base += (size_t)CAT * CAT * 2;
    u16*   l1tl = (u16*)base;    base += (size_t)CAT * CAT * 2;
    u16*   l2th = (u16*)base;    base += (size_t)CAT * CAT * 2;
    u16*   l2tl = (u16*)base;    base += (size_t)CAT * CAT * 2;
    u16*   w2th = (u16*)base;    base += (size_t)CAT * H_FEATS * 2;
    u16*   w2tl = (u16*)base;    base += (size_t)CAT * H_FEATS * 2;
    u16*   l3th = (u16*)base;    base += (size_t)CAT * NUM_CLS * 2;
    u16*   l3tl = (u16*)base;    base += (size_t)CAT * NUM_CLS * 2;
    float* dgo_f = (float*)base; base += (size_t)NNG * 4;
    float* dgi_f = (float*)base; base += (size_t)NNG * 4;
    int*   deg_o = (int*)base;   base += (size_t)NNG * 4;
    int*   deg_i = (int*)base;   base += (size_t)NNG * 4;
    int*   cursor= (int*)base;   base += (size_t)NNG * 4;
    int*   parts = (int*)base;   base += 4096;
    int*   es    = (int*)base;   base += (size_t)TOT_E * 4;
    float* ec    = (float*)base; base += (size_t)TOT_E * 4;

    const int TPB = 256;
    dim3 blk(TPB);
    const int NB_SCAN = (NNG + 255) / 256;
    const int NBY = (N_NODES + 127) / 128;               // 391

    // 1. degree histograms
    hipMemsetAsync(deg_o, 0, 2 * (size_t)NNG * sizeof(int), stream);
    k_deg_i<<<2048, blk, 0, stream>>>(src, deg_o);
    k_deg_i<<<2048, blk, 0, stream>>>(dst, deg_i);
    k_invsqrt_i<<<512, blk, 0, stream>>>(deg_o, dgo_f, 2 * NNG);  // deg_o,deg_i adjacent

    // 2. scan + 3. sort
    k_scan1<<<NB_SCAN, blk, 0, stream>>>(deg_i, cursor, parts);
    k_scan2<<<1, 1024, 0, stream>>>(parts, NB_SCAN);
    k_scan3<<<NB_SCAN, blk, 0, stream>>>(cursor, parts);
    k_esort<<<4096, blk, 0, stream>>>(src, dst, w, dgo_f, cursor, es, ec);

    // 4. splits: in_feat + all weights (transposed)
    k_splita<<<2048, blk, 0, stream>>>(in_feat, S0h, S0l, N_NODES * IN_FEATS / 4);
    k_splitw<<<(IN_FEATS * H_FEATS + 255) / 256, blk, 0, stream>>>(W1, w1th, w1tl, IN_FEATS, H_FEATS);
    k_splitw<<<(CAT * CAT + 255) / 256, blk, 0, stream>>>(l1w, l1th, l1tl, CAT, CAT);
    k_splitw<<<(CAT * CAT + 255) / 256, blk, 0, stream>>>(l2w, l2th, l2tl, CAT, CAT);
    k_splitw<<<(CAT * H_FEATS + 255) / 256, blk, 0, stream>>>(W2, w2th, w2tl, CAT, H_FEATS);
    k_splitw<<<(CAT * NUM_CLS + 255) / 256, blk, 0, stream>>>(l3w, l3th, l3tl, CAT, NUM_CLS);

    const int GATHER_BLKS = (NNG * 64 + TPB - 1) / TPB;

    // 5. P = in_feat @ W1  (MFMA, fp32 out)
    k_mfma<false, false, false><<<NBY, blk, 0, stream>>>(
        S0h, S0l, w1th, w1tl, nullptr, P, nullptr, nullptr,
        N_NODES, H_FEATS, IN_FEATS, 1);
    // 6. conv1 gather -> split bf16 S1
    k_gather<1><<<GATHER_BLKS, blk, 0, stream>>>(P, es, ec, cursor, deg_i, dgi_f,
                                                 nullptr, S1h, S1l);
    // 7. S2 = relu(S1 @ l1w + l1b)
    k_mfma<true, true, true><<<NBY * 4, blk, 0, stream>>>(
        S1h, S1l, l1th, l1tl, l1b, nullptr, S2h, S2l, N_NODES, CAT, CAT, 4);
    // 8. S1 = relu(S2 @ l2w + l2b)
    k_mfma<true, true, true><<<NBY * 4, blk, 0, stream>>>(
        S2h, S2l, l2th, l2tl, l2b, nullptr, S1h, S1l, N_NODES, CAT, CAT, 4);
    // 9. P = S1 @ W2
    k_mfma<false, false, false><<<NBY, blk, 0, stream>>>(
        S1h, S1l, w2th, w2tl, nullptr, P, nullptr, nullptr,
        N_NODES, H_FEATS, CAT, 1);
    // 10. conv2 gather -> split bf16 S2
    k_gather<1><<<GATHER_BLKS, blk, 0, stream>>>(P, es, ec, cursor, deg_i, dgi_f,
                                                 nullptr, S2h, S2l);
    // 11. out = S2 @ l3w + l3b  (N=40, col-guarded staging)
    k_mfma<false, false, true><<<NBY, blk, 0, stream>>>(
        S2h, S2l, l3th, l3tl, l3b, out, nullptr, nullptr,
        N_NODES, NUM_CLS, CAT, 1);
}

// Round 5
// 1335.903 us; speedup vs baseline: 9.3760x; 1.2042x over previous
//
#include <hip/hip_runtime.h>

#define N_NODES  50000
#define G_NUM    4
#define N_EDGES  800000
#define IN_FEATS 256
#define H_FEATS  128
#define NUM_CLS  40
#define CAT      512   // H_FEATS * G_NUM
#define NNG      (G_NUM * N_NODES)   // 200000
#define TOT_E    (G_NUM * N_EDGES)   // 3200000
#define M_PAD    50048               // 391 * 128

typedef unsigned short u16;
typedef __attribute__((ext_vector_type(8))) short s16x8;
typedef __attribute__((ext_vector_type(4))) float f32x4;

// blocked K8-panel layout: element (m,k) -> (k>>3)*(MP*8) + m*8 + (k&7)
__device__ __forceinline__ size_t bo(int m, int k, int MP) {
    return (size_t)(k >> 3) * ((size_t)MP * 8) + (size_t)m * 8 + (k & 7);
}

// ---- bf16 split helpers ----
__device__ __forceinline__ u16 f2bf(float x) {
    unsigned u = __float_as_uint(x);
    unsigned r = (u + 0x7FFFu + ((u >> 16) & 1u)) >> 16;
    return (u16)r;
}
__device__ __forceinline__ float bf2f(u16 h) {
    return __uint_as_float(((unsigned)h) << 16);
}

__device__ __forceinline__ void gld16(const void* g, void* l) {
    __builtin_amdgcn_global_load_lds(
        (const __attribute__((address_space(1))) void*)g,
        (__attribute__((address_space(3))) void*)l, 16, 0, 0);
}

// ---------------- degree accumulation (int) ----------------
__global__ void k_deg_i(const int* __restrict__ idx, int* __restrict__ deg) {
    int stride = gridDim.x * blockDim.x;
    for (int i = blockIdx.x * blockDim.x + threadIdx.x; i < TOT_E; i += stride) {
        int g = i / N_EDGES;
        atomicAdd(&deg[g * N_NODES + idx[i]], 1);
    }
}

__global__ void k_invsqrt_i(const int* __restrict__ d, float* __restrict__ f, int n) {
    int stride = gridDim.x * blockDim.x;
    for (int i = blockIdx.x * blockDim.x + threadIdx.x; i < n; i += stride)
        f[i] = rsqrtf(fmaxf((float)d[i], 1.0f));
}

// ---------------- exclusive scan of deg_in ----------------
__global__ void k_scan1(const int* __restrict__ deg, int* __restrict__ cursor,
                        int* __restrict__ partials) {
    __shared__ int s[256];
    int i = blockIdx.x * 256 + threadIdx.x;
    int v = (i < NNG) ? deg[i] : 0;
    s[threadIdx.x] = v;
    __syncthreads();
    for (int off = 1; off < 256; off <<= 1) {
        int t = (threadIdx.x >= off) ? s[threadIdx.x - off] : 0;
        __syncthreads();
        s[threadIdx.x] += t;
        __syncthreads();
    }
    if (i < NNG) cursor[i] = s[threadIdx.x] - v;
    if (threadIdx.x == 255) partials[blockIdx.x] = s[255];
}
__global__ void k_scan2(int* __restrict__ partials, int n) {
    __shared__ int s[1024];
    int v = (threadIdx.x < n) ? partials[threadIdx.x] : 0;
    s[threadIdx.x] = v;
    __syncthreads();
    for (int off = 1; off < 1024; off <<= 1) {
        int t = (threadIdx.x >= off) ? s[threadIdx.x - off] : 0;
        __syncthreads();
        s[threadIdx.x] += t;
        __syncthreads();
    }
    if (threadIdx.x < n) partials[threadIdx.x] = s[threadIdx.x] - v;
}
__global__ void k_scan3(int* __restrict__ cursor, const int* __restrict__ partials) {
    int i = blockIdx.x * 256 + threadIdx.x;
    if (i < NNG) cursor[i] += partials[blockIdx.x];
}

// ---------------- edge counting-sort by (g,dst) ----------------
__global__ void k_esort(const int* __restrict__ src, const int* __restrict__ dst,
                        const float* __restrict__ w, const float* __restrict__ dgo_f,
                        int* __restrict__ cursor, int* __restrict__ es,
                        float* __restrict__ ec) {
    int stride = gridDim.x * blockDim.x;
    for (int i = blockIdx.x * blockDim.x + threadIdx.x; i < TOT_E; i += stride) {
        int g = i / N_EDGES;
        int s = src[i], d = dst[i];
        int pos = atomicAdd(&cursor[g * N_NODES + d], 1);
        es[pos] = s;
        ec[pos] = w[i] * dgo_f[g * N_NODES + s];
    }
}

// ---------------- gather SpMM: one wave per (g,dst) row ----------------
// SPLIT=1: write blocked bf16 hi/lo (K8-panel layout); SPLIT=0: fp32 row-major H
template<int SPLIT>
__global__ __launch_bounds__(256) void k_gather(
        const float* __restrict__ P, const int* __restrict__ es,
        const float* __restrict__ ec, const int* __restrict__ cursor,
        const int* __restrict__ deg_in, const float* __restrict__ dgi_f,
        float* __restrict__ H, u16* __restrict__ Sh, u16* __restrict__ Sl) {
    int wid = (int)((blockIdx.x * (unsigned)blockDim.x + threadIdx.x) >> 6);
    int lane = threadIdx.x & 63;
    if (wid >= NNG) return;
    int g = wid / N_NODES;
    int d = wid - g * N_NODES;
    int end = cursor[wid];
    int start = end - deg_in[wid];
    float ax = 0.f, ay = 0.f;
    int e = start;
    for (; e + 1 < end; e += 2) {
        int s0 = es[e], s1 = es[e + 1];
        float c0 = ec[e], c1 = ec[e + 1];
        float2 v0 = *reinterpret_cast<const float2*>(&P[(size_t)s0 * H_FEATS + lane * 2]);
        float2 v1 = *reinterpret_cast<const float2*>(&P[(size_t)s1 * H_FEATS + lane * 2]);
        ax += c0 * v0.x + c1 * v1.x;
        ay += c0 * v0.y + c1 * v1.y;
    }
    if (e < end) {
        int s0 = es[e];
        float c0 = ec[e];
        float2 v0 = *reinterpret_cast<const float2*>(&P[(size_t)s0 * H_FEATS + lane * 2]);
        ax += c0 * v0.x;
        ay += c0 * v0.y;
    }
    float sc = dgi_f[wid];
    float rx = fmaxf(ax * sc, 0.f);
    float ry = fmaxf(ay * sc, 0.f);
    if (SPLIT) {
        int k = g * H_FEATS + lane * 2;
        size_t off = bo(d, k, M_PAD);     // k even -> (k&7) even, 2 contiguous
        u16 hx = f2bf(rx), hy = f2bf(ry);
        u16 lx = f2bf(rx - bf2f(hx)), ly = f2bf(ry - bf2f(hy));
        ushort2 hv; hv.x = hx; hv.y = hy;
        ushort2 lv; lv.x = lx; lv.y = ly;
        *reinterpret_cast<ushort2*>(&Sh[off]) = hv;
        *reinterpret_cast<ushort2*>(&Sl[off]) = lv;
    } else {
        float2 r; r.x = rx; r.y = ry;
        *reinterpret_cast<float2*>(&H[(size_t)d * CAT + g * H_FEATS + lane * 2]) = r;
    }
}

// ---------------- weight split: W[K][N] -> blocked Th/Tl over cols (NP padded, zero-fill) ----------------
__global__ void k_splitw(const float* __restrict__ W, u16* __restrict__ Th,
                         u16* __restrict__ Tl, int K, int N, int NP) {
    int i = blockIdx.x * 256 + threadIdx.x;
    if (i >= K * NP) return;
    int k = i / NP, n = i - k * NP;
    float x = (n < N) ? W[(size_t)k * N + n] : 0.0f;
    u16 h = f2bf(x);
    size_t off = bo(n, k, NP);
    Th[off] = h;
    Tl[off] = f2bf(x - bf2f(h));
}

// ---------------- activation split: X[N_NODES][Kdim] fp32 -> blocked bf16 hi/lo ----------------
__global__ void k_splita(const float* __restrict__ X, u16* __restrict__ Xh,
                         u16* __restrict__ Xl, int Kdim) {
    int kq = Kdim >> 2;
    int total = N_NODES * kq;
    int stride = gridDim.x * blockDim.x;
    for (int i = blockIdx.x * blockDim.x + threadIdx.x; i < total; i += stride) {
        int m = i / kq;
        int k = (i - m * kq) * 4;
        float4 v = *reinterpret_cast<const float4*>(&X[(size_t)m * Kdim + k]);
        ushort4 h, l;
        h.x = f2bf(v.x); l.x = f2bf(v.x - bf2f(h.x));
        h.y = f2bf(v.y); l.y = f2bf(v.y - bf2f(h.y));
        h.z = f2bf(v.z); l.z = f2bf(v.z - bf2f(h.z));
        h.w = f2bf(v.w); l.w = f2bf(v.w - bf2f(h.w));
        size_t off = bo(m, k, M_PAD);     // k%8 in {0,4}: 4 contiguous
        *reinterpret_cast<ushort4*>(&Xh[off]) = h;
        *reinterpret_cast<ushort4*>(&Xl[off]) = l;
    }
}

// ---------------- bf16x3 split-precision MFMA GEMM, global_load_lds staging ----------------
// Operands in K8-panel blocked layout (A over MP rows, B over NP cols).
// C = act(A @ B^T + bias). 128x128 tile, BK=32, 4 waves 2x2; XCD-swizzled 1-D grid.
template<bool RELU, bool SPLIT_OUT, bool HASBIAS>
__global__ __launch_bounds__(256, 1) void k_mfma(
        const u16* __restrict__ Ah, const u16* __restrict__ Al,
        const u16* __restrict__ Bth, const u16* __restrict__ Btl,
        const float* __restrict__ bias,
        float* __restrict__ Cf, u16* __restrict__ Ch, u16* __restrict__ Cl,
        int M, int N, int K, int nbx, int NP) {
    __shared__ u16 sA[2][4][128][8];   // [hi/lo][k8][row][8]  16 KB
    __shared__ u16 sB[2][4][128][8];   // [hi/lo][k8][col][8]  16 KB

    // bijective XCD swizzle (m204)
    int nwg = gridDim.x;
    int q = nwg >> 3, r = nwg & 7;
    int xcd = blockIdx.x & 7, rest = blockIdx.x >> 3;
    int lg = (xcd < r ? xcd * (q + 1) : r * (q + 1) + (xcd - r) * q) + rest;
    int bx = lg % nbx, by = lg / nbx;

    const int tid = threadIdx.x;
    const int lane = tid & 63;
    const int wave = tid >> 6;
    const int wr = wave >> 1, wc = wave & 1;
    const int l15 = lane & 15, l4 = lane >> 4;
    const int bm = by * 128, bn = bx * 128;

    const int sidx = tid & 127;        // row/col this thread stages
    const int sw = tid >> 7;           // 0 = hi plane, 1 = lo plane
    const int shalf = sidx & 64;       // wave-uniform half base (0 or 64)
    const u16* As = sw ? Al : Ah;
    const u16* Bs = sw ? Btl : Bth;
    // per-lane global element bases (lane-contiguous: consecutive sidx -> +16B)
    const size_t aoff = (size_t)(bm + sidx) * 8;
    const size_t boff = (size_t)(bn + sidx) * 8;
    const size_t apan = (size_t)M_PAD * 8;   // elements per k8-panel (A side)
    const size_t bpan = (size_t)NP * 8;      // elements per k8-panel (B side)

    f32x4 acc[4][4];
    #pragma unroll
    for (int m = 0; m < 4; m++)
        #pragma unroll
        for (int n = 0; n < 4; n++)
            acc[m][n] = (f32x4){0.f, 0.f, 0.f, 0.f};

    for (int k0 = 0; k0 < K; k0 += 32) {
        int p0 = k0 >> 3;
        #pragma unroll
        for (int k8 = 0; k8 < 4; k8++) {
            gld16(As + (size_t)(p0 + k8) * apan + aoff, &sA[sw][k8][shalf][0]);
            gld16(Bs + (size_t)(p0 + k8) * bpan + boff, &sB[sw][k8][shalf][0]);
        }
        __syncthreads();   // vmcnt(0) drain: tile staged
        s16x8 fah[4], fal[4], fbh[4], fbl[4];
        #pragma unroll
        for (int m = 0; m < 4; m++) {
            fah[m] = *reinterpret_cast<const s16x8*>(&sA[0][l4][wr * 64 + m * 16 + l15][0]);
            fal[m] = *reinterpret_cast<const s16x8*>(&sA[1][l4][wr * 64 + m * 16 + l15][0]);
        }
        #pragma unroll
        for (int n = 0; n < 4; n++) {
            fbh[n] = *reinterpret_cast<const s16x8*>(&sB[0][l4][wc * 64 + n * 16 + l15][0]);
            fbl[n] = *reinterpret_cast<const s16x8*>(&sB[1][l4][wc * 64 + n * 16 + l15][0]);
        }
        #pragma unroll
        for (int m = 0; m < 4; m++)
            #pragma unroll
            for (int n = 0; n < 4; n++) {
                acc[m][n] = __builtin_amdgcn_mfma_f32_16x16x32_bf16(fah[m], fbh[n], acc[m][n], 0, 0, 0);
                acc[m][n] = __builtin_amdgcn_mfma_f32_16x16x32_bf16(fah[m], fbl[n], acc[m][n], 0, 0, 0);
                acc[m][n] = __builtin_amdgcn_mfma_f32_16x16x32_bf16(fal[m], fbh[n], acc[m][n], 0, 0, 0);
            }
        __syncthreads();   // all reads done before next overwrite
    }

    // epilogue: D col = lane&15, row = (lane>>4)*4 + r   [m89 layout]
    #pragma unroll
    for (int n = 0; n < 4; n++) {
        int col = bn + wc * 64 + n * 16 + l15;
        if (col >= N) continue;
        float bs = HASBIAS ? bias[col] : 0.0f;
        #pragma unroll
        for (int m = 0; m < 4; m++) {
            #pragma unroll
            for (int r = 0; r < 4; r++) {
                int row = bm + wr * 64 + m * 16 + l4 * 4 + r;
                if (row < M) {
                    float x = acc[m][n][r] + bs;
                    if (RELU) x = fmaxf(x, 0.f);
                    if (SPLIT_OUT) {
                        size_t off = bo(row, col, M_PAD);
                        u16 h = f2bf(x);
                        Ch[off] = h;
                        Cl[off] = f2bf(x - bf2f(h));
                    } else {
                        Cf[(size_t)row * N + col] = x;
                    }
                }
            }
        }
    }
}

extern "C" void kernel_launch(void* const* d_in, const int* in_sizes, int n_in,
                              void* d_out, int out_size, void* d_ws, size_t ws_size,
                              hipStream_t stream) {
    const float* in_feat = (const float*)d_in[0];
    const int*   src     = (const int*)d_in[1];
    const int*   dst     = (const int*)d_in[2];
    const float* w       = (const float*)d_in[3];
    const float* W1      = (const float*)d_in[4];
    const float* W2      = (const float*)d_in[5];
    const float* l1w     = (const float*)d_in[6];
    const float* l1b     = (const float*)d_in[7];
    const float* l2w     = (const float*)d_in[8];
    const float* l2b     = (const float*)d_in[9];
    const float* l3w     = (const float*)d_in[10];
    const float* l3b     = (const float*)d_in[11];
    float* out = (float*)d_out;

    // ---- workspace carve ----
    char* base = (char*)d_ws;
    float* P    = (float*)base;  base += (size_t)M_PAD * H_FEATS * 4;        // 25.6 MB
    u16*   S1h  = (u16*)base;    base += (size_t)M_PAD * CAT * 2;            // 51.25 MB
    u16*   S1l  = (u16*)base;    base += (size_t)M_PAD * CAT * 2;
    u16*   S2h  = (u16*)base;    base += (size_t)M_PAD * CAT * 2;
    u16*   S2l  = (u16*)base;    base += (size_t)M_PAD * CAT * 2;
    // S0 (split in_feat, M_PAD x 256 blocked) aliases S2h region (dead before S2 written)
    u16*   S0h  = S2h;
    u16*   S0l  = S2h + (size_t)M_PAD * IN_FEATS;
    u16*   w1th = (u16*)base;    base += (size_t)IN_FEATS * H_FEATS * 2;
    u16*   w1tl = (u16*)base;    base += (size_t)IN_FEATS * H_FEATS * 2;
    u16*   l1th = (u16*)base;    base += (size_t)CAT * CAT * 2;
    u16*   l1tl = (u16*)base;    base += (size_t)CAT * CAT * 2;
    u16*   l2th = (u16*)base;    base += (size_t)CAT * CAT * 2;
    u16*   l2tl = (u16*)base;    base += (size_t)CAT * CAT * 2;
    u16*   w2th = (u16*)base;    base += (size_t)CAT * H_FEATS * 2;
    u16*   w2tl = (u16*)base;    base += (size_t)CAT * H_FEATS * 2;
    u16*   l3th = (u16*)base;    base += (size_t)CAT * 128 * 2;              // NP=128 padded
    u16*   l3tl = (u16*)base;    base += (size_t)CAT * 128 * 2;
    float* dgo_f = (float*)base; base += (size_t)NNG * 4;
    float* dgi_f = (float*)base; base += (size_t)NNG * 4;
    int*   deg_o = (int*)base;   base += (size_t)NNG * 4;
    int*   deg_i = (int*)base;   base += (size_t)NNG * 4;
    int*   cursor= (int*)base;   base += (size_t)NNG * 4;
    int*   parts = (int*)base;   base += 4096;
    int*   es    = (int*)base;   base += (size_t)TOT_E * 4;
    float* ec    = (float*)base; base += (size_t)TOT_E * 4;

    const int TPB = 256;
    dim3 blk(TPB);
    const int NB_SCAN = (NNG + 255) / 256;
    const int NBY = (N_NODES + 127) / 128;               // 391

    // 1. degree histograms
    hipMemsetAsync(deg_o, 0, 2 * (size_t)NNG * sizeof(int), stream);
    k_deg_i<<<2048, blk, 0, stream>>>(src, deg_o);
    k_deg_i<<<2048, blk, 0, stream>>>(dst, deg_i);
    k_invsqrt_i<<<512, blk, 0, stream>>>(deg_o, dgo_f, 2 * NNG);  // deg_o,deg_i adjacent

    // 2. scan + 3. sort
    k_scan1<<<NB_SCAN, blk, 0, stream>>>(deg_i, cursor, parts);
    k_scan2<<<1, 1024, 0, stream>>>(parts, NB_SCAN);
    k_scan3<<<NB_SCAN, blk, 0, stream>>>(cursor, parts);
    k_esort<<<4096, blk, 0, stream>>>(src, dst, w, dgo_f, cursor, es, ec);

    // 4. splits (blocked layouts)
    k_splita<<<2048, blk, 0, stream>>>(in_feat, S0h, S0l, IN_FEATS);
    k_splitw<<<(IN_FEATS * 128 + 255) / 256, blk, 0, stream>>>(W1, w1th, w1tl, IN_FEATS, H_FEATS, 128);
    k_splitw<<<(CAT * CAT + 255) / 256, blk, 0, stream>>>(l1w, l1th, l1tl, CAT, CAT, CAT);
    k_splitw<<<(CAT * CAT + 255) / 256, blk, 0, stream>>>(l2w, l2th, l2tl, CAT, CAT, CAT);
    k_splitw<<<(CAT * 128 + 255) / 256, blk, 0, stream>>>(W2, w2th, w2tl, CAT, H_FEATS, 128);
    k_splitw<<<(CAT * 128 + 255) / 256, blk, 0, stream>>>(l3w, l3th, l3tl, CAT, NUM_CLS, 128);

    const int GATHER_BLKS = (NNG * 64 + TPB - 1) / TPB;

    // 5. P = in_feat @ W1  (MFMA, fp32 out)
    k_mfma<false, false, false><<<NBY, blk, 0, stream>>>(
        S0h, S0l, w1th, w1tl, nullptr, P, nullptr, nullptr,
        N_NODES, H_FEATS, IN_FEATS, 1, 128);
    // 6. conv1 gather -> blocked split bf16 S1
    k_gather<1><<<GATHER_BLKS, blk, 0, stream>>>(P, es, ec, cursor, deg_i, dgi_f,
                                                 nullptr, S1h, S1l);
    // 7. S2 = relu(S1 @ l1w + l1b)
    k_mfma<true, true, true><<<NBY * 4, blk, 0, stream>>>(
        S1h, S1l, l1th, l1tl, l1b, nullptr, S2h, S2l, N_NODES, CAT, CAT, 4, CAT);
    // 8. S1 = relu(S2 @ l2w + l2b)
    k_mfma<true, true, true><<<NBY * 4, blk, 0, stream>>>(
        S2h, S2l, l2th, l2tl, l2b, nullptr, S1h, S1l, N_NODES, CAT, CAT, 4, CAT);
    // 9. P = S1 @ W2
    k_mfma<false, false, false><<<NBY, blk, 0, stream>>>(
        S1h, S1l, w2th, w2tl, nullptr, P, nullptr, nullptr,
        N_NODES, H_FEATS, CAT, 1, 128);
    // 10. conv2 gather -> blocked split bf16 S2
    k_gather<1><<<GATHER_BLKS, blk, 0, stream>>>(P, es, ec, cursor, deg_i, dgi_f,
                                                 nullptr, S2h, S2l);
    // 11. out = S2 @ l3w + l3b  (N=40 real, NP=128 padded)
    k_mfma<false, false, true><<<NBY, blk, 0, stream>>>(
        S2h, S2l, l3th, l3tl, l3b, out, nullptr, nullptr,
        N_NODES, NUM_CLS, CAT, 1, 128);
}

// Round 6
// 1229.238 us; speedup vs baseline: 10.1896x; 1.0868x over previous
//
#include <hip/hip_runtime.h>

#define N_NODES  50000
#define G_NUM    4
#define N_EDGES  800000
#define IN_FEATS 256
#define H_FEATS  128
#define NUM_CLS  40
#define CAT      512   // H_FEATS * G_NUM
#define NNG      (G_NUM * N_NODES)   // 200000
#define TOT_E    (G_NUM * N_EDGES)   // 3200000
#define M_PAD    50048               // 391 * 128

typedef unsigned short u16;
typedef __attribute__((ext_vector_type(8))) short s16x8;
typedef __attribute__((ext_vector_type(4))) float f32x4;

// blocked K8-panel layout: element (m,k) -> (k>>3)*(MP*8) + m*8 + (k&7)
__device__ __forceinline__ size_t bo(int m, int k, int MP) {
    return (size_t)(k >> 3) * ((size_t)MP * 8) + (size_t)m * 8 + (k & 7);
}

// ---- bf16 split helpers ----
__device__ __forceinline__ u16 f2bf(float x) {
    unsigned u = __float_as_uint(x);
    unsigned r = (u + 0x7FFFu + ((u >> 16) & 1u)) >> 16;
    return (u16)r;
}
__device__ __forceinline__ float bf2f(u16 h) {
    return __uint_as_float(((unsigned)h) << 16);
}

__device__ __forceinline__ void gld16(const void* g, void* l) {
    __builtin_amdgcn_global_load_lds(
        (const __attribute__((address_space(1))) void*)g,
        (__attribute__((address_space(3))) void*)l, 16, 0, 0);
}

// ---------------- degree accumulation: both src and dst in one pass ----------------
__global__ void k_deg2(const int* __restrict__ src, const int* __restrict__ dst,
                       int* __restrict__ deg_o, int* __restrict__ deg_i) {
    int stride = gridDim.x * blockDim.x;
    for (int i = blockIdx.x * blockDim.x + threadIdx.x; i < TOT_E; i += stride) {
        int g = i / N_EDGES;
        atomicAdd(&deg_o[g * N_NODES + src[i]], 1);
        atomicAdd(&deg_i[g * N_NODES + dst[i]], 1);
    }
}

__global__ void k_invsqrt_i(const int* __restrict__ d, float* __restrict__ f, int n) {
    int stride = gridDim.x * blockDim.x;
    for (int i = blockIdx.x * blockDim.x + threadIdx.x; i < n; i += stride)
        f[i] = rsqrtf(fmaxf((float)d[i], 1.0f));
}

// ---------------- exclusive scan of deg_in ----------------
__global__ void k_scan1(const int* __restrict__ deg, int* __restrict__ cursor,
                        int* __restrict__ partials) {
    __shared__ int s[256];
    int i = blockIdx.x * 256 + threadIdx.x;
    int v = (i < NNG) ? deg[i] : 0;
    s[threadIdx.x] = v;
    __syncthreads();
    for (int off = 1; off < 256; off <<= 1) {
        int t = (threadIdx.x >= off) ? s[threadIdx.x - off] : 0;
        __syncthreads();
        s[threadIdx.x] += t;
        __syncthreads();
    }
    if (i < NNG) cursor[i] = s[threadIdx.x] - v;
    if (threadIdx.x == 255) partials[blockIdx.x] = s[255];
}
__global__ void k_scan2(int* __restrict__ partials, int n) {
    __shared__ int s[1024];
    int v = (threadIdx.x < n) ? partials[threadIdx.x] : 0;
    s[threadIdx.x] = v;
    __syncthreads();
    for (int off = 1; off < 1024; off <<= 1) {
        int t = (threadIdx.x >= off) ? s[threadIdx.x - off] : 0;
        __syncthreads();
        s[threadIdx.x] += t;
        __syncthreads();
    }
    if (threadIdx.x < n) partials[threadIdx.x] = s[threadIdx.x] - v;
}
__global__ void k_scan3(int* __restrict__ cursor, const int* __restrict__ partials) {
    int i = blockIdx.x * 256 + threadIdx.x;
    if (i < NNG) cursor[i] += partials[blockIdx.x];
}

// ---------------- edge counting-sort by (g,dst): writes interleaved (src, coef) ----------------
__global__ void k_esort(const int* __restrict__ src, const int* __restrict__ dst,
                        const float* __restrict__ w, const float* __restrict__ dgo_f,
                        int* __restrict__ cursor, int2* __restrict__ ee) {
    int stride = gridDim.x * blockDim.x;
    for (int i = blockIdx.x * blockDim.x + threadIdx.x; i < TOT_E; i += stride) {
        int g = i / N_EDGES;
        int s = src[i], d = dst[i];
        int pos = atomicAdd(&cursor[g * N_NODES + d], 1);
        int2 m;
        m.x = s;
        m.y = __float_as_int(w[i] * dgo_f[g * N_NODES + s]);
        ee[pos] = m;
    }
}

// ---------------- gather SpMM: one wave per (g,dst) row, 2 edges/step, float4/lane ----------------
// SPLIT=1: blocked bf16 hi/lo out; SPLIT=0: fp32 row-major H out
template<int SPLIT>
__global__ __launch_bounds__(256) void k_gather(
        const float* __restrict__ P, const int2* __restrict__ ee,
        const int* __restrict__ cursor, const int* __restrict__ deg_in,
        const float* __restrict__ dgi_f,
        float* __restrict__ H, u16* __restrict__ Sh, u16* __restrict__ Sl) {
    int wid = (int)((blockIdx.x * (unsigned)blockDim.x + threadIdx.x) >> 6);
    if (wid >= NNG) return;
    int lane = threadIdx.x & 63;
    int h = lane >> 5;          // which of the 2 concurrent edges
    int fl = lane & 31;         // feature chunk: floats [fl*4, fl*4+4)
    int g = wid / N_NODES;
    int d = wid - g * N_NODES;
    int end = cursor[wid];
    int start = end - deg_in[wid];
    const float4* P4 = reinterpret_cast<const float4*>(P);

    float4 acc = make_float4(0.f, 0.f, 0.f, 0.f);
    int e = start;
    for (; e + 3 < end; e += 4) {          // 2 steps unconditionally valid
        int2 m0 = ee[e + h];
        int2 m1 = ee[e + 2 + h];
        float4 v0 = P4[(size_t)m0.x * 32 + fl];
        float4 v1 = P4[(size_t)m1.x * 32 + fl];
        float c0 = __int_as_float(m0.y);
        float c1 = __int_as_float(m1.y);
        acc.x += c0 * v0.x + c1 * v1.x;
        acc.y += c0 * v0.y + c1 * v1.y;
        acc.z += c0 * v0.z + c1 * v1.z;
        acc.w += c0 * v0.w + c1 * v1.w;
    }
    for (; e < end; e += 2) {
        int ei = e + h;
        if (ei < end) {
            int2 m0 = ee[ei];
            float4 v0 = P4[(size_t)m0.x * 32 + fl];
            float c0 = __int_as_float(m0.y);
            acc.x += c0 * v0.x; acc.y += c0 * v0.y;
            acc.z += c0 * v0.z; acc.w += c0 * v0.w;
        }
    }
    // combine the two half-wave partial sums into lanes 0..31
    acc.x += __shfl_down(acc.x, 32);
    acc.y += __shfl_down(acc.y, 32);
    acc.z += __shfl_down(acc.z, 32);
    acc.w += __shfl_down(acc.w, 32);
    if (h == 0) {
        float sc = dgi_f[wid];
        float4 r;
        r.x = fmaxf(acc.x * sc, 0.f);
        r.y = fmaxf(acc.y * sc, 0.f);
        r.z = fmaxf(acc.z * sc, 0.f);
        r.w = fmaxf(acc.w * sc, 0.f);
        if (SPLIT) {
            int k = g * H_FEATS + fl * 4;
            size_t off = bo(d, k, M_PAD);   // k%8 in {0,4}: 4 contiguous
            ushort4 hv, lv;
            hv.x = f2bf(r.x); lv.x = f2bf(r.x - bf2f(hv.x));
            hv.y = f2bf(r.y); lv.y = f2bf(r.y - bf2f(hv.y));
            hv.z = f2bf(r.z); lv.z = f2bf(r.z - bf2f(hv.z));
            hv.w = f2bf(r.w); lv.w = f2bf(r.w - bf2f(hv.w));
            *reinterpret_cast<ushort4*>(&Sh[off]) = hv;
            *reinterpret_cast<ushort4*>(&Sl[off]) = lv;
        } else {
            *reinterpret_cast<float4*>(&H[(size_t)d * CAT + g * H_FEATS + fl * 4]) = r;
        }
    }
}

// ---------------- weight split: W[K][N] -> blocked Th/Tl over cols (NP padded, zero-fill) ----------------
__global__ void k_splitw(const float* __restrict__ W, u16* __restrict__ Th,
                         u16* __restrict__ Tl, int K, int N, int NP) {
    int i = blockIdx.x * 256 + threadIdx.x;
    if (i >= K * NP) return;
    int k = i / NP, n = i - k * NP;
    float x = (n < N) ? W[(size_t)k * N + n] : 0.0f;
    u16 h = f2bf(x);
    size_t off = bo(n, k, NP);
    Th[off] = h;
    Tl[off] = f2bf(x - bf2f(h));
}

// ---------------- activation split: X[N_NODES][Kdim] fp32 -> blocked bf16 hi/lo ----------------
__global__ void k_splita(const float* __restrict__ X, u16* __restrict__ Xh,
                         u16* __restrict__ Xl, int Kdim) {
    int kq = Kdim >> 2;
    int total = N_NODES * kq;
    int stride = gridDim.x * blockDim.x;
    for (int i = blockIdx.x * blockDim.x + threadIdx.x; i < total; i += stride) {
        int m = i / kq;
        int k = (i - m * kq) * 4;
        float4 v = *reinterpret_cast<const float4*>(&X[(size_t)m * Kdim + k]);
        ushort4 h, l;
        h.x = f2bf(v.x); l.x = f2bf(v.x - bf2f(h.x));
        h.y = f2bf(v.y); l.y = f2bf(v.y - bf2f(h.y));
        h.z = f2bf(v.z); l.z = f2bf(v.z - bf2f(h.z));
        h.w = f2bf(v.w); l.w = f2bf(v.w - bf2f(h.w));
        size_t off = bo(m, k, M_PAD);     // k%8 in {0,4}: 4 contiguous
        *reinterpret_cast<ushort4*>(&Xh[off]) = h;
        *reinterpret_cast<ushort4*>(&Xl[off]) = l;
    }
}

// ---------------- bf16x3 split-precision MFMA GEMM, global_load_lds staging ----------------
template<bool RELU, bool SPLIT_OUT, bool HASBIAS>
__global__ __launch_bounds__(256, 1) void k_mfma(
        const u16* __restrict__ Ah, const u16* __restrict__ Al,
        const u16* __restrict__ Bth, const u16* __restrict__ Btl,
        const float* __restrict__ bias,
        float* __restrict__ Cf, u16* __restrict__ Ch, u16* __restrict__ Cl,
        int M, int N, int K, int nbx, int NP) {
    __shared__ u16 sA[2][4][128][8];   // [hi/lo][k8][row][8]  16 KB
    __shared__ u16 sB[2][4][128][8];   // [hi/lo][k8][col][8]  16 KB

    // bijective XCD swizzle (m204)
    int nwg = gridDim.x;
    int q = nwg >> 3, r = nwg & 7;
    int xcd = blockIdx.x & 7, rest = blockIdx.x >> 3;
    int lg = (xcd < r ? xcd * (q + 1) : r * (q + 1) + (xcd - r) * q) + rest;
    int bx = lg % nbx, by = lg / nbx;

    const int tid = threadIdx.x;
    const int lane = tid & 63;
    const int wave = tid >> 6;
    const int wr = wave >> 1, wc = wave & 1;
    const int l15 = lane & 15, l4 = lane >> 4;
    const int bm = by * 128, bn = bx * 128;

    const int sidx = tid & 127;        // row/col this thread stages
    const int sw = tid >> 7;           // 0 = hi plane, 1 = lo plane
    const int shalf = sidx & 64;       // wave-uniform half base (0 or 64)
    const u16* As = sw ? Al : Ah;
    const u16* Bs = sw ? Btl : Bth;
    const size_t aoff = (size_t)(bm + sidx) * 8;
    const size_t boff = (size_t)(bn + sidx) * 8;
    const size_t apan = (size_t)M_PAD * 8;
    const size_t bpan = (size_t)NP * 8;

    f32x4 acc[4][4];
    #pragma unroll
    for (int m = 0; m < 4; m++)
        #pragma unroll
        for (int n = 0; n < 4; n++)
            acc[m][n] = (f32x4){0.f, 0.f, 0.f, 0.f};

    for (int k0 = 0; k0 < K; k0 += 32) {
        int p0 = k0 >> 3;
        #pragma unroll
        for (int k8 = 0; k8 < 4; k8++) {
            gld16(As + (size_t)(p0 + k8) * apan + aoff, &sA[sw][k8][shalf][0]);
            gld16(Bs + (size_t)(p0 + k8) * bpan + boff, &sB[sw][k8][shalf][0]);
        }
        __syncthreads();   // vmcnt(0) drain: tile staged
        s16x8 fah[4], fal[4], fbh[4], fbl[4];
        #pragma unroll
        for (int m = 0; m < 4; m++) {
            fah[m] = *reinterpret_cast<const s16x8*>(&sA[0][l4][wr * 64 + m * 16 + l15][0]);
            fal[m] = *reinterpret_cast<const s16x8*>(&sA[1][l4][wr * 64 + m * 16 + l15][0]);
        }
        #pragma unroll
        for (int n = 0; n < 4; n++) {
            fbh[n] = *reinterpret_cast<const s16x8*>(&sB[0][l4][wc * 64 + n * 16 + l15][0]);
            fbl[n] = *reinterpret_cast<const s16x8*>(&sB[1][l4][wc * 64 + n * 16 + l15][0]);
        }
        #pragma unroll
        for (int m = 0; m < 4; m++)
            #pragma unroll
            for (int n = 0; n < 4; n++) {
                acc[m][n] = __builtin_amdgcn_mfma_f32_16x16x32_bf16(fah[m], fbh[n], acc[m][n], 0, 0, 0);
                acc[m][n] = __builtin_amdgcn_mfma_f32_16x16x32_bf16(fah[m], fbl[n], acc[m][n], 0, 0, 0);
                acc[m][n] = __builtin_amdgcn_mfma_f32_16x16x32_bf16(fal[m], fbh[n], acc[m][n], 0, 0, 0);
            }
        __syncthreads();   // all reads done before next overwrite
    }

    // epilogue: D col = lane&15, row = (lane>>4)*4 + r   [m89 layout]
    #pragma unroll
    for (int n = 0; n < 4; n++) {
        int col = bn + wc * 64 + n * 16 + l15;
        if (col >= N) continue;
        float bs = HASBIAS ? bias[col] : 0.0f;
        #pragma unroll
        for (int m = 0; m < 4; m++) {
            #pragma unroll
            for (int r = 0; r < 4; r++) {
                int row = bm + wr * 64 + m * 16 + l4 * 4 + r;
                if (row < M) {
                    float x = acc[m][n][r] + bs;
                    if (RELU) x = fmaxf(x, 0.f);
                    if (SPLIT_OUT) {
                        size_t off = bo(row, col, M_PAD);
                        u16 h = f2bf(x);
                        Ch[off] = h;
                        Cl[off] = f2bf(x - bf2f(h));
                    } else {
                        Cf[(size_t)row * N + col] = x;
                    }
                }
            }
        }
    }
}

extern "C" void kernel_launch(void* const* d_in, const int* in_sizes, int n_in,
                              void* d_out, int out_size, void* d_ws, size_t ws_size,
                              hipStream_t stream) {
    const float* in_feat = (const float*)d_in[0];
    const int*   src     = (const int*)d_in[1];
    const int*   dst     = (const int*)d_in[2];
    const float* w       = (const float*)d_in[3];
    const float* W1      = (const float*)d_in[4];
    const float* W2      = (const float*)d_in[5];
    const float* l1w     = (const float*)d_in[6];
    const float* l1b     = (const float*)d_in[7];
    const float* l2w     = (const float*)d_in[8];
    const float* l2b     = (const float*)d_in[9];
    const float* l3w     = (const float*)d_in[10];
    const float* l3b     = (const float*)d_in[11];
    float* out = (float*)d_out;

    // ---- workspace carve ----
    char* base = (char*)d_ws;
    float* P    = (float*)base;  base += (size_t)M_PAD * H_FEATS * 4;        // 25.6 MB
    u16*   S1h  = (u16*)base;    base += (size_t)M_PAD * CAT * 2;            // 51.25 MB
    u16*   S1l  = (u16*)base;    base += (size_t)M_PAD * CAT * 2;
    u16*   S2h  = (u16*)base;    base += (size_t)M_PAD * CAT * 2;
    u16*   S2l  = (u16*)base;    base += (size_t)M_PAD * CAT * 2;
    u16*   S0h  = S2h;                                   // alias: dead before S2 written
    u16*   S0l  = S2h + (size_t)M_PAD * IN_FEATS;
    u16*   w1th = (u16*)base;    base += (size_t)IN_FEATS * H_FEATS * 2;
    u16*   w1tl = (u16*)base;    base += (size_t)IN_FEATS * H_FEATS * 2;
    u16*   l1th = (u16*)base;    base += (size_t)CAT * CAT * 2;
    u16*   l1tl = (u16*)base;    base += (size_t)CAT * CAT * 2;
    u16*   l2th = (u16*)base;    base += (size_t)CAT * CAT * 2;
    u16*   l2tl = (u16*)base;    base += (size_t)CAT * CAT * 2;
    u16*   w2th = (u16*)base;    base += (size_t)CAT * H_FEATS * 2;
    u16*   w2tl = (u16*)base;    base += (size_t)CAT * H_FEATS * 2;
    u16*   l3th = (u16*)base;    base += (size_t)CAT * 128 * 2;              // NP=128 padded
    u16*   l3tl = (u16*)base;    base += (size_t)CAT * 128 * 2;
    float* dgo_f = (float*)base; base += (size_t)NNG * 4;
    float* dgi_f = (float*)base; base += (size_t)NNG * 4;
    int*   deg_o = (int*)base;   base += (size_t)NNG * 4;
    int*   deg_i = (int*)base;   base += (size_t)NNG * 4;
    int*   cursor= (int*)base;   base += (size_t)NNG * 4;
    int*   parts = (int*)base;   base += 4096;
    int2*  ee    = (int2*)base;  base += (size_t)TOT_E * 8;

    const int TPB = 256;
    dim3 blk(TPB);
    const int NB_SCAN = (NNG + 255) / 256;
    const int NBY = (N_NODES + 127) / 128;               // 391

    // 1. degree histograms (one fused pass)
    hipMemsetAsync(deg_o, 0, 2 * (size_t)NNG * sizeof(int), stream);
    k_deg2<<<4096, blk, 0, stream>>>(src, dst, deg_o, deg_i);
    k_invsqrt_i<<<512, blk, 0, stream>>>(deg_o, dgo_f, 2 * NNG);  // deg_o,deg_i adjacent

    // 2. scan + 3. sort
    k_scan1<<<NB_SCAN, blk, 0, stream>>>(deg_i, cursor, parts);
    k_scan2<<<1, 1024, 0, stream>>>(parts, NB_SCAN);
    k_scan3<<<NB_SCAN, blk, 0, stream>>>(cursor, parts);
    k_esort<<<4096, blk, 0, stream>>>(src, dst, w, dgo_f, cursor, ee);

    // 4. splits (blocked layouts)
    k_splita<<<2048, blk, 0, stream>>>(in_feat, S0h, S0l, IN_FEATS);
    k_splitw<<<(IN_FEATS * 128 + 255) / 256, blk, 0, stream>>>(W1, w1th, w1tl, IN_FEATS, H_FEATS, 128);
    k_splitw<<<(CAT * CAT + 255) / 256, blk, 0, stream>>>(l1w, l1th, l1tl, CAT, CAT, CAT);
    k_splitw<<<(CAT * CAT + 255) / 256, blk, 0, stream>>>(l2w, l2th, l2tl, CAT, CAT, CAT);
    k_splitw<<<(CAT * 128 + 255) / 256, blk, 0, stream>>>(W2, w2th, w2tl, CAT, H_FEATS, 128);
    k_splitw<<<(CAT * 128 + 255) / 256, blk, 0, stream>>>(l3w, l3th, l3tl, CAT, NUM_CLS, 128);

    const int GATHER_BLKS = (NNG * 64 + TPB - 1) / TPB;  // 50000

    // 5. P = in_feat @ W1  (MFMA, fp32 out)
    k_mfma<false, false, false><<<NBY, blk, 0, stream>>>(
        S0h, S0l, w1th, w1tl, nullptr, P, nullptr, nullptr,
        N_NODES, H_FEATS, IN_FEATS, 1, 128);
    // 6. conv1 gather -> blocked split bf16 S1
    k_gather<1><<<GATHER_BLKS, blk, 0, stream>>>(P, ee, cursor, deg_i, dgi_f,
                                                 nullptr, S1h, S1l);
    // 7. S2 = relu(S1 @ l1w + l1b)
    k_mfma<true, true, true><<<NBY * 4, blk, 0, stream>>>(
        S1h, S1l, l1th, l1tl, l1b, nullptr, S2h, S2l, N_NODES, CAT, CAT, 4, CAT);
    // 8. S1 = relu(S2 @ l2w + l2b)
    k_mfma<true, true, true><<<NBY * 4, blk, 0, stream>>>(
        S2h, S2l, l2th, l2tl, l2b, nullptr, S1h, S1l, N_NODES, CAT, CAT, 4, CAT);
    // 9. P = S1 @ W2
    k_mfma<false, false, false><<<NBY, blk, 0, stream>>>(
        S1h, S1l, w2th, w2tl, nullptr, P, nullptr, nullptr,
        N_NODES, H_FEATS, CAT, 1, 128);
    // 10. conv2 gather -> blocked split bf16 S2
    k_gather<1><<<GATHER_BLKS, blk, 0, stream>>>(P, ee, cursor, deg_i, dgi_f,
                                                 nullptr, S2h, S2l);
    // 11. out = S2 @ l3w + l3b  (N=40 real, NP=128 padded)
    k_mfma<false, false, true><<<NBY, blk, 0, stream>>>(
        S2h, S2l, l3th, l3tl, l3b, out, nullptr, nullptr,
        N_NODES, NUM_CLS, CAT, 1, 128);
}

// Round 7
// 1036.507 us; speedup vs baseline: 12.0843x; 1.1859x over previous
//
#include <hip/hip_runtime.h>

#define N_NODES  50000
#define G_NUM    4
#define N_EDGES  800000
#define IN_FEATS 256
#define H_FEATS  128
#define NUM_CLS  40
#define CAT      512   // H_FEATS * G_NUM
#define NNG      (G_NUM * N_NODES)   // 200000
#define TOT_E    (G_NUM * N_EDGES)   // 3200000
#define M_PAD    50048               // 391 * 128
#define HNB      32                  // histogram chunks per (array, graph)
#define HWORDS   (N_NODES / 2)       // 25000 packed u32 words

typedef unsigned short u16;
typedef __attribute__((ext_vector_type(8))) short s16x8;
typedef __attribute__((ext_vector_type(4))) float f32x4;

// blocked K8-panel layout: element (m,k) -> (k>>3)*(MP*8) + m*8 + (k&7)
__device__ __forceinline__ size_t bo(int m, int k, int MP) {
    return (size_t)(k >> 3) * ((size_t)MP * 8) + (size_t)m * 8 + (k & 7);
}

// ---- bf16 split helpers ----
__device__ __forceinline__ u16 f2bf(float x) {
    unsigned u = __float_as_uint(x);
    unsigned r = (u + 0x7FFFu + ((u >> 16) & 1u)) >> 16;
    return (u16)r;
}
__device__ __forceinline__ float bf2f(u16 h) {
    return __uint_as_float(((unsigned)h) << 16);
}

__device__ __forceinline__ void gld16(const void* g, void* l) {
    __builtin_amdgcn_global_load_lds(
        (const __attribute__((address_space(1))) void*)g,
        (__attribute__((address_space(3))) void*)l, 16, 0, 0);
}

// ---------------- LDS-histogram degree counting ----------------
// 256 blocks; block b: a = b/HNB in [0,8) -> (isdst = a>>2, g = a&3); chunk c = b%HNB.
// Packed 2xu16 counters in 100 KB dynamic LDS; coalesced dump to histbuf[a][c][word].
__global__ __launch_bounds__(256) void k_hist(const int* __restrict__ src,
                                              const int* __restrict__ dst,
                                              unsigned* __restrict__ histbuf) {
    extern __shared__ unsigned h[];           // HWORDS = 25000 words (100 KB)
    for (int i = threadIdx.x; i < HWORDS; i += 256) h[i] = 0;
    __syncthreads();
    int a = blockIdx.x / HNB;
    int c = blockIdx.x - a * HNB;
    int g = a & 3, isdst = a >> 2;
    const int* idx = (isdst ? dst : src) + (size_t)g * N_EDGES + c * (N_EDGES / HNB);
    for (int i = threadIdx.x; i < N_EDGES / HNB; i += 256) {
        int v = idx[i];
        atomicAdd(&h[v >> 1], (v & 1) ? 0x10000u : 1u);
    }
    __syncthreads();
    unsigned* outp = histbuf + ((size_t)a * HNB + c) * HWORDS;
    for (int i = threadIdx.x; i < HWORDS; i += 256) outp[i] = h[i];
}

// reduce HNB chunk-copies, unpack u16 pairs -> deg (deg_o[4][N] then deg_i[4][N])
__global__ void k_histred(const unsigned* __restrict__ histbuf, int* __restrict__ deg) {
    int i = blockIdx.x * 256 + threadIdx.x;   // global word id
    if (i >= 8 * HWORDS) return;
    int a = i / HWORDS;
    int wd = i - a * HWORDS;
    const unsigned* p = histbuf + (size_t)a * HNB * HWORDS + wd;
    unsigned lo = 0, hi = 0;
    #pragma unroll 4
    for (int c = 0; c < HNB; c++) {
        unsigned v = p[(size_t)c * HWORDS];
        lo += v & 0xFFFFu;
        hi += v >> 16;
    }
    deg[(size_t)a * N_NODES + 2 * wd]     = (int)lo;
    deg[(size_t)a * N_NODES + 2 * wd + 1] = (int)hi;
}

__global__ void k_invsqrt_i(const int* __restrict__ d, float* __restrict__ f, int n) {
    int stride = gridDim.x * blockDim.x;
    for (int i = blockIdx.x * blockDim.x + threadIdx.x; i < n; i += stride)
        f[i] = rsqrtf(fmaxf((float)d[i], 1.0f));
}

// ---------------- exclusive scan of deg_in ----------------
__global__ void k_scan1(const int* __restrict__ deg, int* __restrict__ cursor,
                        int* __restrict__ partials) {
    __shared__ int s[256];
    int i = blockIdx.x * 256 + threadIdx.x;
    int v = (i < NNG) ? deg[i] : 0;
    s[threadIdx.x] = v;
    __syncthreads();
    for (int off = 1; off < 256; off <<= 1) {
        int t = (threadIdx.x >= off) ? s[threadIdx.x - off] : 0;
        __syncthreads();
        s[threadIdx.x] += t;
        __syncthreads();
    }
    if (i < NNG) cursor[i] = s[threadIdx.x] - v;
    if (threadIdx.x == 255) partials[blockIdx.x] = s[255];
}
__global__ void k_scan2(int* __restrict__ partials, int n) {
    __shared__ int s[1024];
    int v = (threadIdx.x < n) ? partials[threadIdx.x] : 0;
    s[threadIdx.x] = v;
    __syncthreads();
    for (int off = 1; off < 1024; off <<= 1) {
        int t = (threadIdx.x >= off) ? s[threadIdx.x - off] : 0;
        __syncthreads();
        s[threadIdx.x] += t;
        __syncthreads();
    }
    if (threadIdx.x < n) partials[threadIdx.x] = s[threadIdx.x] - v;
}
__global__ void k_scan3(int* __restrict__ cursor, const int* __restrict__ partials) {
    int i = blockIdx.x * 256 + threadIdx.x;
    if (i < NNG) cursor[i] += partials[blockIdx.x];
}

// ---------------- edge counting-sort by (g,dst): writes interleaved (src, coef) ----------------
__global__ void k_esort(const int* __restrict__ src, const int* __restrict__ dst,
                        const float* __restrict__ w, const float* __restrict__ dgo_f,
                        int* __restrict__ cursor, int2* __restrict__ ee) {
    int stride = gridDim.x * blockDim.x;
    for (int i = blockIdx.x * blockDim.x + threadIdx.x; i < TOT_E; i += stride) {
        int g = i / N_EDGES;
        int s = src[i], d = dst[i];
        int pos = atomicAdd(&cursor[g * N_NODES + d], 1);
        int2 m;
        m.x = s;
        m.y = __float_as_int(w[i] * dgo_f[g * N_NODES + s]);
        ee[pos] = m;
    }
}

// ---------------- gather SpMM: one wave per (g,dst) row, 2 edges/step, float4/lane ----------------
template<int SPLIT>
__global__ __launch_bounds__(256) void k_gather(
        const float* __restrict__ P, const int2* __restrict__ ee,
        const int* __restrict__ cursor, const int* __restrict__ deg_in,
        const float* __restrict__ dgi_f,
        float* __restrict__ H, u16* __restrict__ Sh, u16* __restrict__ Sl) {
    int wid = (int)((blockIdx.x * (unsigned)blockDim.x + threadIdx.x) >> 6);
    if (wid >= NNG) return;
    int lane = threadIdx.x & 63;
    int h = lane >> 5;          // which of the 2 concurrent edges
    int fl = lane & 31;         // feature chunk: floats [fl*4, fl*4+4)
    int g = wid / N_NODES;
    int d = wid - g * N_NODES;
    int end = cursor[wid];
    int start = end - deg_in[wid];
    const float4* P4 = reinterpret_cast<const float4*>(P);

    float4 acc = make_float4(0.f, 0.f, 0.f, 0.f);
    int e = start;
    for (; e + 3 < end; e += 4) {
        int2 m0 = ee[e + h];
        int2 m1 = ee[e + 2 + h];
        float4 v0 = P4[(size_t)m0.x * 32 + fl];
        float4 v1 = P4[(size_t)m1.x * 32 + fl];
        float c0 = __int_as_float(m0.y);
        float c1 = __int_as_float(m1.y);
        acc.x += c0 * v0.x + c1 * v1.x;
        acc.y += c0 * v0.y + c1 * v1.y;
        acc.z += c0 * v0.z + c1 * v1.z;
        acc.w += c0 * v0.w + c1 * v1.w;
    }
    for (; e < end; e += 2) {
        int ei = e + h;
        if (ei < end) {
            int2 m0 = ee[ei];
            float4 v0 = P4[(size_t)m0.x * 32 + fl];
            float c0 = __int_as_float(m0.y);
            acc.x += c0 * v0.x; acc.y += c0 * v0.y;
            acc.z += c0 * v0.z; acc.w += c0 * v0.w;
        }
    }
    acc.x += __shfl_down(acc.x, 32);
    acc.y += __shfl_down(acc.y, 32);
    acc.z += __shfl_down(acc.z, 32);
    acc.w += __shfl_down(acc.w, 32);
    if (h == 0) {
        float sc = dgi_f[wid];
        float4 r;
        r.x = fmaxf(acc.x * sc, 0.f);
        r.y = fmaxf(acc.y * sc, 0.f);
        r.z = fmaxf(acc.z * sc, 0.f);
        r.w = fmaxf(acc.w * sc, 0.f);
        if (SPLIT) {
            int k = g * H_FEATS + fl * 4;
            size_t off = bo(d, k, M_PAD);   // k%8 in {0,4}: 4 contiguous
            ushort4 hv, lv;
            hv.x = f2bf(r.x); lv.x = f2bf(r.x - bf2f(hv.x));
            hv.y = f2bf(r.y); lv.y = f2bf(r.y - bf2f(hv.y));
            hv.z = f2bf(r.z); lv.z = f2bf(r.z - bf2f(hv.z));
            hv.w = f2bf(r.w); lv.w = f2bf(r.w - bf2f(hv.w));
            *reinterpret_cast<ushort4*>(&Sh[off]) = hv;
            *reinterpret_cast<ushort4*>(&Sl[off]) = lv;
        } else {
            *reinterpret_cast<float4*>(&H[(size_t)d * CAT + g * H_FEATS + fl * 4]) = r;
        }
    }
}

// ---------------- weight split: W[K][N] -> blocked Th/Tl over cols (NP padded, zero-fill) ----------------
__global__ void k_splitw(const float* __restrict__ W, u16* __restrict__ Th,
                         u16* __restrict__ Tl, int K, int N, int NP) {
    int i = blockIdx.x * 256 + threadIdx.x;
    if (i >= K * NP) return;
    int k = i / NP, n = i - k * NP;
    float x = (n < N) ? W[(size_t)k * N + n] : 0.0f;
    u16 h = f2bf(x);
    size_t off = bo(n, k, NP);
    Th[off] = h;
    Tl[off] = f2bf(x - bf2f(h));
}

// ---------------- activation split: X[N_NODES][Kdim] fp32 -> blocked bf16 hi/lo ----------------
__global__ void k_splita(const float* __restrict__ X, u16* __restrict__ Xh,
                         u16* __restrict__ Xl, int Kdim) {
    int kq = Kdim >> 2;
    int total = N_NODES * kq;
    int stride = gridDim.x * blockDim.x;
    for (int i = blockIdx.x * blockDim.x + threadIdx.x; i < total; i += stride) {
        int m = i / kq;
        int k = (i - m * kq) * 4;
        float4 v = *reinterpret_cast<const float4*>(&X[(size_t)m * Kdim + k]);
        ushort4 h, l;
        h.x = f2bf(v.x); l.x = f2bf(v.x - bf2f(h.x));
        h.y = f2bf(v.y); l.y = f2bf(v.y - bf2f(h.y));
        h.z = f2bf(v.z); l.z = f2bf(v.z - bf2f(h.z));
        h.w = f2bf(v.w); l.w = f2bf(v.w - bf2f(h.w));
        size_t off = bo(m, k, M_PAD);
        *reinterpret_cast<ushort4*>(&Xh[off]) = h;
        *reinterpret_cast<ushort4*>(&Xl[off]) = l;
    }
}

// ---------------- bf16x3 split-precision MFMA GEMM, global_load_lds staging ----------------
template<bool RELU, bool SPLIT_OUT, bool HASBIAS>
__global__ __launch_bounds__(256, 1) void k_mfma(
        const u16* __restrict__ Ah, const u16* __restrict__ Al,
        const u16* __restrict__ Bth, const u16* __restrict__ Btl,
        const float* __restrict__ bias,
        float* __restrict__ Cf, u16* __restrict__ Ch, u16* __restrict__ Cl,
        int M, int N, int K, int nbx, int NP) {
    __shared__ u16 sA[2][4][128][8];   // [hi/lo][k8][row][8]  16 KB
    __shared__ u16 sB[2][4][128][8];   // [hi/lo][k8][col][8]  16 KB

    // bijective XCD swizzle (m204)
    int nwg = gridDim.x;
    int q = nwg >> 3, r = nwg & 7;
    int xcd = blockIdx.x & 7, rest = blockIdx.x >> 3;
    int lg = (xcd < r ? xcd * (q + 1) : r * (q + 1) + (xcd - r) * q) + rest;
    int bx = lg % nbx, by = lg / nbx;

    const int tid = threadIdx.x;
    const int lane = tid & 63;
    const int wave = tid >> 6;
    const int wr = wave >> 1, wc = wave & 1;
    const int l15 = lane & 15, l4 = lane >> 4;
    const int bm = by * 128, bn = bx * 128;

    const int sidx = tid & 127;
    const int sw = tid >> 7;           // 0 = hi plane, 1 = lo plane
    const int shalf = sidx & 64;       // wave-uniform half base
    const u16* As = sw ? Al : Ah;
    const u16* Bs = sw ? Btl : Bth;
    const size_t aoff = (size_t)(bm + sidx) * 8;
    const size_t boff = (size_t)(bn + sidx) * 8;
    const size_t apan = (size_t)M_PAD * 8;
    const size_t bpan = (size_t)NP * 8;

    f32x4 acc[4][4];
    #pragma unroll
    for (int m = 0; m < 4; m++)
        #pragma unroll
        for (int n = 0; n < 4; n++)
            acc[m][n] = (f32x4){0.f, 0.f, 0.f, 0.f};

    for (int k0 = 0; k0 < K; k0 += 32) {
        int p0 = k0 >> 3;
        #pragma unroll
        for (int k8 = 0; k8 < 4; k8++) {
            gld16(As + (size_t)(p0 + k8) * apan + aoff, &sA[sw][k8][shalf][0]);
            gld16(Bs + (size_t)(p0 + k8) * bpan + boff, &sB[sw][k8][shalf][0]);
        }
        __syncthreads();   // vmcnt(0) drain: tile staged
        s16x8 fah[4], fal[4], fbh[4], fbl[4];
        #pragma unroll
        for (int m = 0; m < 4; m++) {
            fah[m] = *reinterpret_cast<const s16x8*>(&sA[0][l4][wr * 64 + m * 16 + l15][0]);
            fal[m] = *reinterpret_cast<const s16x8*>(&sA[1][l4][wr * 64 + m * 16 + l15][0]);
        }
        #pragma unroll
        for (int n = 0; n < 4; n++) {
            fbh[n] = *reinterpret_cast<const s16x8*>(&sB[0][l4][wc * 64 + n * 16 + l15][0]);
            fbl[n] = *reinterpret_cast<const s16x8*>(&sB[1][l4][wc * 64 + n * 16 + l15][0]);
        }
        #pragma unroll
        for (int m = 0; m < 4; m++)
            #pragma unroll
            for (int n = 0; n < 4; n++) {
                acc[m][n] = __builtin_amdgcn_mfma_f32_16x16x32_bf16(fah[m], fbh[n], acc[m][n], 0, 0, 0);
                acc[m][n] = __builtin_amdgcn_mfma_f32_16x16x32_bf16(fah[m], fbl[n], acc[m][n], 0, 0, 0);
                acc[m][n] = __builtin_amdgcn_mfma_f32_16x16x32_bf16(fal[m], fbh[n], acc[m][n], 0, 0, 0);
            }
        __syncthreads();
    }

    // epilogue: D col = lane&15, row = (lane>>4)*4 + r   [m89 layout]
    #pragma unroll
    for (int n = 0; n < 4; n++) {
        int col = bn + wc * 64 + n * 16 + l15;
        if (col >= N) continue;
        float bs = HASBIAS ? bias[col] : 0.0f;
        #pragma unroll
        for (int m = 0; m < 4; m++) {
            #pragma unroll
            for (int r = 0; r < 4; r++) {
                int row = bm + wr * 64 + m * 16 + l4 * 4 + r;
                if (row < M) {
                    float x = acc[m][n][r] + bs;
                    if (RELU) x = fmaxf(x, 0.f);
                    if (SPLIT_OUT) {
                        size_t off = bo(row, col, M_PAD);
                        u16 h = f2bf(x);
                        Ch[off] = h;
                        Cl[off] = f2bf(x - bf2f(h));
                    } else {
                        Cf[(size_t)row * N + col] = x;
                    }
                }
            }
        }
    }
}

extern "C" void kernel_launch(void* const* d_in, const int* in_sizes, int n_in,
                              void* d_out, int out_size, void* d_ws, size_t ws_size,
                              hipStream_t stream) {
    const float* in_feat = (const float*)d_in[0];
    const int*   src     = (const int*)d_in[1];
    const int*   dst     = (const int*)d_in[2];
    const float* w       = (const float*)d_in[3];
    const float* W1      = (const float*)d_in[4];
    const float* W2      = (const float*)d_in[5];
    const float* l1w     = (const float*)d_in[6];
    const float* l1b     = (const float*)d_in[7];
    const float* l2w     = (const float*)d_in[8];
    const float* l2b     = (const float*)d_in[9];
    const float* l3w     = (const float*)d_in[10];
    const float* l3b     = (const float*)d_in[11];
    float* out = (float*)d_out;

    // ---- workspace carve ----
    char* base = (char*)d_ws;
    float* P    = (float*)base;  base += (size_t)M_PAD * H_FEATS * 4;        // 25.6 MB
    u16*   S1h  = (u16*)base;    base += (size_t)M_PAD * CAT * 2;            // 51.25 MB
    u16*   S1l  = (u16*)base;    base += (size_t)M_PAD * CAT * 2;
    u16*   S2h  = (u16*)base;    base += (size_t)M_PAD * CAT * 2;
    u16*   S2l  = (u16*)base;    base += (size_t)M_PAD * CAT * 2;
    u16*   S0h  = S2h;                                   // alias: dead before S2 written
    u16*   S0l  = S2h + (size_t)M_PAD * IN_FEATS;
    unsigned* histbuf = (unsigned*)S1h;                  // alias: 25.6 MB, dead before S1 written
    u16*   w1th = (u16*)base;    base += (size_t)IN_FEATS * H_FEATS * 2;
    u16*   w1tl = (u16*)base;    base += (size_t)IN_FEATS * H_FEATS * 2;
    u16*   l1th = (u16*)base;    base += (size_t)CAT * CAT * 2;
    u16*   l1tl = (u16*)base;    base += (size_t)CAT * CAT * 2;
    u16*   l2th = (u16*)base;    base += (size_t)CAT * CAT * 2;
    u16*   l2tl = (u16*)base;    base += (size_t)CAT * CAT * 2;
    u16*   w2th = (u16*)base;    base += (size_t)CAT * H_FEATS * 2;
    u16*   w2tl = (u16*)base;    base += (size_t)CAT * H_FEATS * 2;
    u16*   l3th = (u16*)base;    base += (size_t)CAT * 128 * 2;              // NP=128 padded
    u16*   l3tl = (u16*)base;    base += (size_t)CAT * 128 * 2;
    float* dgo_f = (float*)base; base += (size_t)NNG * 4;
    float* dgi_f = (float*)base; base += (size_t)NNG * 4;
    int*   deg_o = (int*)base;   base += (size_t)NNG * 4;   // deg_o[4][N] then deg_i[4][N]
    int*   deg_i = (int*)base;   base += (size_t)NNG * 4;
    int*   cursor= (int*)base;   base += (size_t)NNG * 4;
    int*   parts = (int*)base;   base += 4096;
    int2*  ee    = (int2*)base;  base += (size_t)TOT_E * 8;

    const int TPB = 256;
    dim3 blk(TPB);
    const int NB_SCAN = (NNG + 255) / 256;
    const int NBY = (N_NODES + 127) / 128;               // 391

    // 1. degree histograms via LDS (no global atomics, no memset)
    k_hist<<<2 * G_NUM * HNB, blk, HWORDS * 4, stream>>>(src, dst, histbuf);
    k_histred<<<(8 * HWORDS + 255) / 256, blk, 0, stream>>>(histbuf, deg_o);
    k_invsqrt_i<<<512, blk, 0, stream>>>(deg_o, dgo_f, 2 * NNG);  // deg_o,deg_i adjacent

    // 2. scan + 3. sort
    k_scan1<<<NB_SCAN, blk, 0, stream>>>(deg_i, cursor, parts);
    k_scan2<<<1, 1024, 0, stream>>>(parts, NB_SCAN);
    k_scan3<<<NB_SCAN, blk, 0, stream>>>(cursor, parts);
    k_esort<<<4096, blk, 0, stream>>>(src, dst, w, dgo_f, cursor, ee);

    // 4. splits (blocked layouts)
    k_splita<<<2048, blk, 0, stream>>>(in_feat, S0h, S0l, IN_FEATS);
    k_splitw<<<(IN_FEATS * 128 + 255) / 256, blk, 0, stream>>>(W1, w1th, w1tl, IN_FEATS, H_FEATS, 128);
    k_splitw<<<(CAT * CAT + 255) / 256, blk, 0, stream>>>(l1w, l1th, l1tl, CAT, CAT, CAT);
    k_splitw<<<(CAT * CAT + 255) / 256, blk, 0, stream>>>(l2w, l2th, l2tl, CAT, CAT, CAT);
    k_splitw<<<(CAT * 128 + 255) / 256, blk, 0, stream>>>(W2, w2th, w2tl, CAT, H_FEATS, 128);
    k_splitw<<<(CAT * 128 + 255) / 256, blk, 0, stream>>>(l3w, l3th, l3tl, CAT, NUM_CLS, 128);

    const int GATHER_BLKS = (NNG * 64 + TPB - 1) / TPB;  // 50000

    // 5. P = in_feat @ W1  (MFMA, fp32 out)
    k_mfma<false, false, false><<<NBY, blk, 0, stream>>>(
        S0h, S0l, w1th, w1tl, nullptr, P, nullptr, nullptr,
        N_NODES, H_FEATS, IN_FEATS, 1, 128);
    // 6. conv1 gather -> blocked split bf16 S1 (histbuf dead from here)
    k_gather<1><<<GATHER_BLKS, blk, 0, stream>>>(P, ee, cursor, deg_i, dgi_f,
                                                 nullptr, S1h, S1l);
    // 7. S2 = relu(S1 @ l1w + l1b)
    k_mfma<true, true, true><<<NBY * 4, blk, 0, stream>>>(
        S1h, S1l, l1th, l1tl, l1b, nullptr, S2h, S2l, N_NODES, CAT, CAT, 4, CAT);
    // 8. S1 = relu(S2 @ l2w + l2b)
    k_mfma<true, true, true><<<NBY * 4, blk, 0, stream>>>(
        S2h, S2l, l2th, l2tl, l2b, nullptr, S1h, S1l, N_NODES, CAT, CAT, 4, CAT);
    // 9. P = S1 @ W2
    k_mfma<false, false, false><<<NBY, blk, 0, stream>>>(
        S1h, S1l, w2th, w2tl, nullptr, P, nullptr, nullptr,
        N_NODES, H_FEATS, CAT, 1, 128);
    // 10. conv2 gather -> blocked split bf16 S2
    k_gather<1><<<GATHER_BLKS, blk, 0, stream>>>(P, ee, cursor, deg_i, dgi_f,
                                                 nullptr, S2h, S2l);
    // 11. out = S2 @ l3w + l3b  (N=40 real, NP=128 padded)
    k_mfma<false, false, true><<<NBY, blk, 0, stream>>>(
        S2h, S2l, l3th, l3tl, l3b, out, nullptr, nullptr,
        N_NODES, NUM_CLS, CAT, 1, 128);
}